// Round 11
// baseline (290.871 us; speedup 1.0000x reference)
//
#include <hip/hip_runtime.h>
#include <hip/hip_fp16.h>

#define EPS 1e-8f
#define NU_MOL 1.5e-5f
#define NPB 512            // nodes per bucket (9-bit rl)
#define MAXNB 256          // max buckets (N <= 131072, 17-bit col pack)
#define NBLK 4096          // edge-chunk blocks for scatter
#define CMAX 1664          // max edges per block chunk (E <= 6.81M)
#define KMAX 7             // ceil(CMAX/256)
#define CH 2048            // accum chunk entries
#define SPLIT 6            // entry-slices per bucket in accum

// ===================== helpers =====================

union U32H2 { unsigned u; __half2 h; };

__device__ inline unsigned packh2(float a, float b) {
    U32H2 x; x.h = __halves2half2(__float2half_rn(a), __float2half_rn(b));
    return x.u;
}
__device__ inline float2 unpackh2(unsigned u) {
    U32H2 x; x.u = u;
    return make_float2(__low2float(x.h), __high2float(x.h));
}
__device__ inline unsigned bf16rne(float f) {
    unsigned u = __float_as_uint(f);
    u += 0x7FFFu + ((u >> 16) & 1u);
    return u >> 16;
}
__device__ inline float bf16dec(unsigned h) {
    return __uint_as_float(h << 16);
}

// ===================== common =====================

__global__ void detect_idx_dtype(const void* eidx, int N, int* flag) {
    const long long* ll = (const long long*)eidx;
    int is64 = 1;
    for (int i = 0; i < 16; ++i) {
        long long v = ll[i];
        if (v < 0 || v >= (long long)N) { is64 = 0; break; }
    }
    *flag = is64;
}

__global__ void finalize_kernel(const double* __restrict__ d,
                                const double* __restrict__ smooth_slots,
                                int N, int E, float* __restrict__ out)
{
    double smooth = 0.0;
    for (int i = 0; i < 64; ++i) smooth += smooth_slots[i];
    double dN = (double)N;
    double n_wall = d[5] > 1.0 ? d[5] : 1.0;
    double total = 1.0  * d[0] / (4.0 * dN)
                 + 0.1  * d[1] / dN
                 + 0.1  * d[2] / dN
                 + 0.05 * d[3] / dN
                 + 0.05 * d[4] / dN
                 + 0.05 * d[6] / n_wall
                 + 0.01 * smooth / (4.0 * (double)E)
                 + 0.02 * d[7] / n_wall;
    out[0] = (float)total;
}

// ===================== fast path =====================

// Pass 1 (was pass 3): streaming scatter with ATOMIC ARENA RESERVATION.
// Each block: LDS histogram -> one global atomicAdd per nonempty bucket to
// reserve a contiguous run in that bucket's fixed-capacity arena region ->
// local counting sort -> coalesced run stores. No prefix-sum pipeline.
// Bucket b's region: vals[b*cap .. b*cap+cap); final gcur[b] = bucket count.
__global__ __launch_bounds__(256) void scatter_kernel(
    const void* __restrict__ eidx, const float2* __restrict__ eattr,
    int E, int N, int NB, int cap, const int* __restrict__ flag,
    unsigned* __restrict__ gcur, uint2* __restrict__ vals)
{
    __shared__ unsigned hist[MAXNB];    // histogram -> scan0
    __shared__ unsigned rstart[MAXNB];  // reserved run start (within bucket)
    __shared__ unsigned cur[MAXNB];
    __shared__ unsigned gb2[MAXNB];
    __shared__ uint2 pl[CMAX];
    __shared__ unsigned char bb[CMAX];
    __shared__ unsigned wt[4];

    const int t = threadIdx.x;
    const int blk = blockIdx.x;
    const int lane = t & 63, wv = t >> 6;
    const int is64 = *flag;
    const long long* ll = (const long long*)eidx;
    const int* ii = (const int*)eidx;
    const int chunk = (E + NBLK - 1) / NBLK;
    const int s = blk * chunk;
    const int Cb = min(chunk, E - s);

    hist[t] = 0u;
    __syncthreads();

    // Phase A: rows -> regs, histogram.
    unsigned rr[KMAX];
    #pragma unroll
    for (int k = 0; k < KMAX; ++k) {
        int i = k * 256 + t;
        if (i < Cb) {
            int r = is64 ? (int)ll[s + i] : ii[s + i];
            r = min(max(r, 0), N - 1);
            rr[k] = (unsigned)r;
            atomicAdd(&hist[r >> 9], 1u);
        } else rr[k] = 0xFFFFFFFFu;
    }
    __syncthreads();

    // Reserve arena runs: one global atomic per nonempty bucket.
    unsigned h = hist[t];
    if (t < NB && h > 0u) {
        unsigned rs = atomicAdd(&gcur[t], h);
        // clamp (degenerate/adversarial inputs only; never for uniform graphs)
        if (rs + h > (unsigned)cap) rs = (h <= (unsigned)cap) ? (unsigned)cap - h : 0u;
        rstart[t] = rs;
    } else rstart[t] = 0u;

    // exclusive shfl-scan of hist -> scan0 (no barrier needed before use of h)
    unsigned x = h;
    #pragma unroll
    for (int off = 1; off < 64; off <<= 1) {
        unsigned y = (unsigned)__shfl_up((int)x, off, 64);
        if (lane >= off) x += y;
    }
    if (lane == 63) wt[wv] = x;
    __syncthreads();
    unsigned wadd = 0;
    for (int w = 0; w < wv; ++w) wadd += wt[w];
    unsigned ex = x + wadd - h;
    hist[t] = ex;
    cur[t] = ex;
    gb2[t] = (unsigned)t * (unsigned)cap + rstart[t] - ex;
    __syncthreads();

    // Phase B: sequential coalesced reads, pack payload, stage to sorted slot.
    #pragma unroll
    for (int k = 0; k < KMAX; ++k) {
        int i = k * 256 + t;
        if (i >= Cb) break;
        int e = s + i;
        unsigned r = rr[k];
        unsigned b = r >> 9;
        unsigned rl = r & (NPB - 1);
        int c = is64 ? (int)ll[(long long)E + e] : ii[E + e];
        c = min(max(c, 0), N - 1);
        float2 dxy = eattr[e];
        unsigned pk = (unsigned)c | (rl << 17);
        unsigned pos = atomicAdd(&cur[b], 1u);
        pl[pos] = make_uint2(pk, packh2(dxy.x, dxy.y));
        bb[pos] = (unsigned char)b;
    }
    __syncthreads();

    // Phase C: coalesced stores of sorted slots into reserved arena runs.
    #pragma unroll
    for (int k = 0; k < KMAX; ++k) {
        int p = k * 256 + t;
        if (p >= Cb) break;
        unsigned b = bb[p];
        vals[gb2[b] + (unsigned)p] = pl[p];
    }
}

// Pass 2: gather + physics + in-LDS counting sort + register run-sum.
// Reads bucket region [b*cap, b*cap + gcur[b]); atomic merge into g[5][N].
__global__ __launch_bounds__(512) void accum_kernel(
    const uint2* __restrict__ vals, const unsigned* __restrict__ gcur, int cap,
    const float4* __restrict__ pred, int N,
    float* __restrict__ g /* [5][N] */, double* __restrict__ smooth_slots)
{
    __shared__ uint2 pl[CH];           // 16 KB sorted bf16x4 physics
    __shared__ uint2 ph[NPB];          // 4 KB fp16 pred of bucket rows
    __shared__ unsigned hist[NPB];     // 2 KB
    __shared__ unsigned cur[NPB];      // 2 KB
    __shared__ unsigned wt[8];
    __shared__ double sm[8];

    const int b = blockIdx.x;
    const int t = threadIdx.x;
    const int wv = t >> 6, lane = t & 63;
    const int n0 = b * NPB;

    {   // stage bucket's pred rows as fp16
        int n = n0 + t;
        float4 p = (n < N) ? pred[n] : make_float4(0.f, 0.f, 0.f, 0.f);
        ph[t] = make_uint2(packh2(p.x, p.y), packh2(p.z, p.w));
    }

    unsigned s0 = (unsigned)b * (unsigned)cap;
    unsigned len = min(gcur[b], (unsigned)cap);
    unsigned s = s0 + (unsigned)(((unsigned long long)len * blockIdx.y) / SPLIT);
    unsigned e = s0 + (unsigned)(((unsigned long long)len * (blockIdx.y + 1)) / SPLIT);

    float cnt = 0, sdiv = 0, smx = 0, smy = 0, sstr = 0;
    double smooth = 0.0;

    for (unsigned cs = s; cs < e; cs += CH) {
        const int n = (int)min((unsigned)CH, e - cs);
        hist[t] = 0u;
        __syncthreads();

        // (a) coalesced payload read -> registers + histogram
        uint2 vv[4];
        #pragma unroll
        for (int k = 0; k < 4; ++k) {
            int i = k * 512 + t;
            if (i < n) {
                vv[k] = vals[cs + i];
                atomicAdd(&hist[(vv[k].x >> 17) & (NPB - 1)], 1u);
            } else vv[k].x = 0xFFFFFFFFu;
        }
        __syncthreads();

        // (b) exclusive scan of 512 bins (1/thread): shfl + wave totals
        unsigned v = hist[t];
        unsigned x = v;
        #pragma unroll
        for (int off = 1; off < 64; off <<= 1) {
            unsigned y = (unsigned)__shfl_up((int)x, off, 64);
            if (lane >= off) x += y;
        }
        if (lane == 63) wt[wv] = x;
        __syncthreads();
        unsigned wadd = 0;
        for (int w = 0; w < wv; ++w) wadd += wt[w];
        unsigned incl = x + wadd;
        unsigned ex0 = incl - v;
        cur[t] = ex0;
        cnt += (float)v;               // count from histogram — no atomic
        __syncthreads();

        // (c) gather + physics + scatter to sorted LDS slot
        #pragma unroll
        for (int k = 0; k < 4; ++k) {
            int i = k * 512 + t;
            if (i >= n) break;
            unsigned pk = vv[k].x;
            int col = (int)(pk & 0x1FFFFu);
            unsigned rl = (pk >> 17) & (NPB - 1);
            float2 dxy = unpackh2(vv[k].y);
            float4 pc = pred[col];
            uint2 pru = ph[rl];
            float2 pxy = unpackh2(pru.x);
            float2 pzw = unpackh2(pru.y);
            float du = pc.x - pxy.x, dv = pc.y - pxy.y;
            float dp = pc.z - pzw.x, dn = pc.w - pzw.y;
            float rx  = 1.0f / (dxy.x + EPS);
            float ry  = 1.0f / (dxy.y + EPS);
            float rx2 = 1.0f / (dxy.x * dxy.x + EPS);
            float ry2 = 1.0f / (dxy.y * dxy.y + EPS);
            float du_dx = du * rx, du_dy = du * ry;
            float dv_dx = dv * rx, dv_dy = dv * ry;
            float nu_eff = NU_MOL + pzw.y;
            float sh = du_dy + dv_dx;
            float div_e = du_dx + dv_dy;
            float mx_e  = dp * rx + nu_eff * du * rx2;
            float my_e  = dp * ry + nu_eff * dv * ry2;
            float str_e = 2.0f * (du_dx * du_dx + dv_dy * dv_dy) + sh * sh;
            unsigned pos = atomicAdd(&cur[rl], 1u);
            pl[pos] = make_uint2(bf16rne(div_e) | (bf16rne(mx_e) << 16),
                                 bf16rne(my_e) | (bf16rne(str_e) << 16));
            smooth += (double)(du * du + dv * dv + dp * dp + dn * dn);
        }
        __syncthreads();

        // (d) register run-sum over contiguous run [ex0, incl) — no atomics
        for (unsigned i = ex0; i < incl; ++i) {
            uint2 pv = pl[i];
            sdiv += bf16dec(pv.x & 0xFFFFu);
            smx  += bf16dec(pv.x >> 16);
            smy  += bf16dec(pv.y & 0xFFFFu);
            sstr += bf16dec(pv.y >> 16);
        }
        __syncthreads();
    }

    // merge partials into global node arrays (coalesced low-contention atomics)
    {
        int n = n0 + t;
        if (n < N) {
            atomicAdd(&g[0 * (size_t)N + n], cnt);
            atomicAdd(&g[1 * (size_t)N + n], sdiv);
            atomicAdd(&g[2 * (size_t)N + n], smx);
            atomicAdd(&g[3 * (size_t)N + n], smy);
            atomicAdd(&g[4 * (size_t)N + n], sstr);
        }
    }

    for (int off = 32; off > 0; off >>= 1)
        smooth += __shfl_down(smooth, off);
    if (lane == 0) sm[wv] = smooth;
    __syncthreads();
    if (t == 0) {
        double tot = 0;
        #pragma unroll
        for (int w = 0; w < 8; ++w) tot += sm[w];
        atomicAdd(&smooth_slots[(b * SPLIT + blockIdx.y) & 63], tot);
    }
}

// Pass 3: node losses from g[5][N] + fused finalize (arrival counter).
__global__ __launch_bounds__(256) void node_final_kernel(
    const float* __restrict__ g, const float4* __restrict__ pred,
    const float4* __restrict__ tgt, const unsigned char* __restrict__ wall,
    int N, int E, double* __restrict__ d,
    const double* __restrict__ smooth_slots, unsigned* __restrict__ counter,
    float* __restrict__ out)
{
    int i = blockIdx.x * 256 + threadIdx.x;
    double v0 = 0, v1 = 0, v2 = 0, v3 = 0, v4 = 0, v5 = 0, v6 = 0, v7 = 0;
    if (i < N) {
        float cnt  = g[0 * (size_t)N + i];
        float inv = 1.0f / fmaxf(cnt, 1.0f);
        float div = g[1 * (size_t)N + i] * inv;
        float mx  = g[2 * (size_t)N + i] * inv;
        float my  = g[3 * (size_t)N + i] * inv;
        float sn  = g[4 * (size_t)N + i] * inv;
        float4 p = pred[i];
        float4 tg = tgt[i];
        float prod = p.w * sn;
        float m = wall[i] ? 1.0f : 0.0f;
        float e0 = p.x - tg.x, e1 = p.y - tg.y, e2 = p.z - tg.z, e3 = p.w - tg.w;
        float uv = p.x * p.x + p.y * p.y;
        v0 = (double)(e0 * e0 + e1 * e1 + e2 * e2 + e3 * e3);
        v1 = (double)div * (double)div;
        v2 = (double)mx * (double)mx + (double)my * (double)my;
        v3 = (double)prod * (double)prod;
        v4 = (double)p.w * (double)p.w;
        v5 = (double)m;
        v6 = (double)(m * uv);
        v7 = (double)(m * (uv + p.w * p.w));
    }
    for (int off = 32; off > 0; off >>= 1) {
        v0 += __shfl_down(v0, off); v1 += __shfl_down(v1, off);
        v2 += __shfl_down(v2, off); v3 += __shfl_down(v3, off);
        v4 += __shfl_down(v4, off); v5 += __shfl_down(v5, off);
        v6 += __shfl_down(v6, off); v7 += __shfl_down(v7, off);
    }
    __shared__ double sm[4][8];
    __shared__ int is_last;
    int lane = threadIdx.x & 63, wv = threadIdx.x >> 6;
    if (lane == 0) {
        sm[wv][0] = v0; sm[wv][1] = v1; sm[wv][2] = v2; sm[wv][3] = v3;
        sm[wv][4] = v4; sm[wv][5] = v5; sm[wv][6] = v6; sm[wv][7] = v7;
    }
    __syncthreads();
    if (threadIdx.x < 8) {
        int q = threadIdx.x;
        atomicAdd(&d[q], sm[0][q] + sm[1][q] + sm[2][q] + sm[3][q]);
    }
    __threadfence();
    __syncthreads();
    if (threadIdx.x == 0) {
        unsigned prev = atomicAdd(counter, 1u);
        is_last = (prev == gridDim.x - 1) ? 1 : 0;
    }
    __syncthreads();
    if (is_last && threadIdx.x == 0) {
        __threadfence();
        double dd[8];
        #pragma unroll
        for (int q = 0; q < 8; ++q) dd[q] = atomicAdd(&d[q], 0.0);  // coherent read
        double smooth = 0.0;
        for (int k = 0; k < 64; ++k) smooth += smooth_slots[k];
        double dN = (double)N;
        double n_wall = dd[5] > 1.0 ? dd[5] : 1.0;
        double total = 1.0  * dd[0] / (4.0 * dN)
                     + 0.1  * dd[1] / dN
                     + 0.1  * dd[2] / dN
                     + 0.05 * dd[3] / dN
                     + 0.05 * dd[4] / dN
                     + 0.05 * dd[6] / n_wall
                     + 0.01 * smooth / (4.0 * (double)E)
                     + 0.02 * dd[7] / n_wall;
        out[0] = (float)total;
    }
}

// ===================== fallback path (R1-style, known-correct) =====================

__global__ __launch_bounds__(256) void edge_kernel(
    const void* __restrict__ eidx, const float2* __restrict__ eattr,
    const float4* __restrict__ pred, int E, int N, const int* __restrict__ flag,
    float* __restrict__ a_cnt, float* __restrict__ a_div,
    float* __restrict__ a_mx, float* __restrict__ a_my,
    float* __restrict__ a_str, double* __restrict__ smooth_slots)
{
    const int is64 = *flag;
    const long long* ll = (const long long*)eidx;
    const int* ii = (const int*)eidx;
    double smooth = 0.0;
    const int stride = gridDim.x * blockDim.x;
    for (int e = blockIdx.x * blockDim.x + threadIdx.x; e < E; e += stride) {
        int row, col;
        if (is64) { row = (int)ll[e]; col = (int)ll[(long long)E + e]; }
        else      { row = ii[e];      col = ii[E + e]; }
        row = min(max(row, 0), N - 1);
        col = min(max(col, 0), N - 1);
        float2 dxy = eattr[e];
        float4 pr = pred[row];
        float4 pc = pred[col];
        float du = pc.x - pr.x, dv = pc.y - pr.y;
        float dp = pc.z - pr.z, dn = pc.w - pr.w;
        float rx  = 1.0f / (dxy.x + EPS);
        float ry  = 1.0f / (dxy.y + EPS);
        float rx2 = 1.0f / (dxy.x * dxy.x + EPS);
        float ry2 = 1.0f / (dxy.y * dxy.y + EPS);
        float du_dx = du * rx, du_dy = du * ry;
        float dv_dx = dv * rx, dv_dy = dv * ry;
        float nu_eff = NU_MOL + pr.w;
        atomicAdd(&a_cnt[row], 1.0f);
        atomicAdd(&a_div[row], du_dx + dv_dy);
        atomicAdd(&a_mx[row], dp * rx + nu_eff * du * rx2);
        atomicAdd(&a_my[row], dp * ry + nu_eff * dv * ry2);
        float sh = du_dy + dv_dx;
        atomicAdd(&a_str[row], 2.0f * (du_dx * du_dx + dv_dy * dv_dy) + sh * sh);
        smooth += (double)(du * du + dv * dv + dp * dp + dn * dn);
    }
    for (int off = 32; off > 0; off >>= 1)
        smooth += __shfl_down(smooth, off);
    __shared__ double sm[4];
    int lane = threadIdx.x & 63, wv = threadIdx.x >> 6;
    if (lane == 0) sm[wv] = smooth;
    __syncthreads();
    if (threadIdx.x == 0)
        atomicAdd(&smooth_slots[blockIdx.x & 63], sm[0] + sm[1] + sm[2] + sm[3]);
}

__global__ __launch_bounds__(256) void node_kernel(
    const float4* __restrict__ pred, const float4* __restrict__ tgt,
    const unsigned char* __restrict__ wall, int N,
    const float* __restrict__ a_cnt, const float* __restrict__ a_div,
    const float* __restrict__ a_mx, const float* __restrict__ a_my,
    const float* __restrict__ a_str, double* __restrict__ d)
{
    int i = blockIdx.x * blockDim.x + threadIdx.x;
    double v0 = 0, v1 = 0, v2 = 0, v3 = 0, v4 = 0, v5 = 0, v6 = 0, v7 = 0;
    if (i < N) {
        float4 p = pred[i];
        float4 t = tgt[i];
        float inv = 1.0f / fmaxf(a_cnt[i], 1.0f);
        float div = a_div[i] * inv;
        float mx = a_mx[i] * inv, my = a_my[i] * inv;
        float sn = a_str[i] * inv;
        float prod = p.w * sn;
        float m = wall[i] ? 1.0f : 0.0f;
        float e0 = p.x - t.x, e1 = p.y - t.y, e2 = p.z - t.z, e3 = p.w - t.w;
        float uv = p.x * p.x + p.y * p.y;
        v0 = (double)(e0 * e0 + e1 * e1 + e2 * e2 + e3 * e3);
        v1 = (double)div * (double)div;
        v2 = (double)mx * (double)mx + (double)my * (double)my;
        v3 = (double)prod * (double)prod;
        v4 = (double)p.w * (double)p.w;
        v5 = (double)m;
        v6 = (double)(m * uv);
        v7 = (double)(m * (uv + p.w * p.w));
    }
    for (int off = 32; off > 0; off >>= 1) {
        v0 += __shfl_down(v0, off); v1 += __shfl_down(v1, off);
        v2 += __shfl_down(v2, off); v3 += __shfl_down(v3, off);
        v4 += __shfl_down(v4, off); v5 += __shfl_down(v5, off);
        v6 += __shfl_down(v6, off); v7 += __shfl_down(v7, off);
    }
    __shared__ double sm[4][8];
    int lane = threadIdx.x & 63, wv = threadIdx.x >> 6;
    if (lane == 0) {
        sm[wv][0] = v0; sm[wv][1] = v1; sm[wv][2] = v2; sm[wv][3] = v3;
        sm[wv][4] = v4; sm[wv][5] = v5; sm[wv][6] = v6; sm[wv][7] = v7;
    }
    __syncthreads();
    if (threadIdx.x < 8) {
        int q = threadIdx.x;
        atomicAdd(&d[q], sm[0][q] + sm[1][q] + sm[2][q] + sm[3][q]);
    }
}

// ===================== launch =====================

extern "C" void kernel_launch(void* const* d_in, const int* in_sizes, int n_in,
                              void* d_out, int out_size, void* d_ws, size_t ws_size,
                              hipStream_t stream) {
    const float4* pred = (const float4*)d_in[0];
    const float4* tgt  = (const float4*)d_in[1];
    const float2* eattr = (const float2*)d_in[2];
    const void* eidx = d_in[3];
    const unsigned char* wall = (const unsigned char*)d_in[4];
    int N = in_sizes[0] / 4;
    int E = in_sizes[2] / 2;
    int NB = (N + NPB - 1) / NPB;
    int chunk = (E + NBLK - 1) / NBLK;
    // arena capacity per bucket: mean + 25% slack, 64-aligned
    int cap = (E + NB - 1) / NB;
    cap += cap / 4;
    cap = (cap + 63) & ~63;

    char* ws = (char*)d_ws;
    double* d = (double*)ws;                 // 8 scalars
    double* smooth_slots = d + 8;            // 64 slots
    int* flag = (int*)(ws + 576);
    unsigned* counter = (unsigned*)(ws + 580);
    unsigned* gcur = (unsigned*)(ws + 1024); // 256 bucket cursors

    size_t off = 4096;
    float* g = (float*)(ws + off);            off += (size_t)5 * N * 4;
    off = (off + 15) & ~(size_t)15;
    uint2* vals = (uint2*)(ws + off);         off += (size_t)NB * cap * 8;
    size_t need_fast = off;

    bool fast = (NB <= MAXNB) && (N <= 131072) && (chunk <= CMAX) &&
                (ws_size >= need_fast);

    if (fast) {
        // zero header (scalars, cursors) + g accumulators
        hipMemsetAsync(d_ws, 0, 4096 + (size_t)5 * N * 4, stream);
        detect_idx_dtype<<<1, 1, 0, stream>>>(eidx, N, flag);
        scatter_kernel<<<NBLK, 256, 0, stream>>>(eidx, eattr, E, N, NB, cap, flag,
                                                 gcur, vals);
        accum_kernel<<<dim3(NB, SPLIT), 512, 0, stream>>>(vals, gcur, cap, pred, N,
                                                          g, smooth_slots);
        node_final_kernel<<<(N + 255) / 256, 256, 0, stream>>>(g, pred, tgt, wall,
                                                               N, E, d,
                                                               smooth_slots, counter,
                                                               (float*)d_out);
    } else {
        float* arrays = (float*)(ws + 1024);
        float* a_cnt = arrays + (size_t)0 * N;
        float* a_div = arrays + (size_t)1 * N;
        float* a_mx  = arrays + (size_t)2 * N;
        float* a_my  = arrays + (size_t)3 * N;
        float* a_str = arrays + (size_t)4 * N;
        size_t zbytes = 1024 + (size_t)5 * N * sizeof(float);
        hipMemsetAsync(d_ws, 0, zbytes, stream);
        detect_idx_dtype<<<1, 1, 0, stream>>>(eidx, N, flag);
        edge_kernel<<<4096, 256, 0, stream>>>(eidx, eattr, pred, E, N, flag,
                                              a_cnt, a_div, a_mx, a_my, a_str,
                                              smooth_slots);
        node_kernel<<<(N + 255) / 256, 256, 0, stream>>>(pred, tgt, wall, N,
                                                         a_cnt, a_div, a_mx, a_my,
                                                         a_str, d);
        finalize_kernel<<<1, 1, 0, stream>>>(d, smooth_slots, N, E, (float*)d_out);
    }
}

// Round 12
// 274.934 us; speedup vs baseline: 1.0580x; 1.0580x over previous
//
#include <hip/hip_runtime.h>
#include <hip/hip_fp16.h>

#define EPS 1e-8f
#define NU_MOL 1.5e-5f
#define NPB 512            // nodes per bucket (9-bit rl)
#define MAXNB 256          // max buckets (N <= 131072, 17-bit col pack)
#define NBP 256            // padded row stride of counts matrix
#define NBLK 4096          // edge-chunk blocks for count/scatter
#define CMAX 1664          // max edges per block chunk (E <= 6.81M)
#define KMAX 7             // ceil(CMAX/256)
#define CH 2048            // accum chunk entries
#define SPLIT 6            // entry-slices per bucket in accum
#define NGRP 64            // block-groups for hierarchical scan
#define GRP 64             // rows per group; NGRP*GRP == NBLK

// ===================== helpers =====================

union U32H2 { unsigned u; __half2 h; };

__device__ inline unsigned packh2(float a, float b) {
    U32H2 x; x.h = __halves2half2(__float2half_rn(a), __float2half_rn(b));
    return x.u;
}
__device__ inline float2 unpackh2(unsigned u) {
    U32H2 x; x.u = u;
    return make_float2(__low2float(x.h), __high2float(x.h));
}
__device__ inline unsigned bf16rne(float f) {
    unsigned u = __float_as_uint(f);
    u += 0x7FFFu + ((u >> 16) & 1u);
    return u >> 16;
}
__device__ inline float bf16dec(unsigned h) {
    return __uint_as_float(h << 16);
}

// ===================== common =====================

__global__ void detect_idx_dtype(const void* eidx, int N, int* flag) {
    const long long* ll = (const long long*)eidx;
    int is64 = 1;
    for (int i = 0; i < 16; ++i) {
        long long v = ll[i];
        if (v < 0 || v >= (long long)N) { is64 = 0; break; }
    }
    *flag = is64;
}

__global__ void finalize_kernel(const double* __restrict__ d,
                                const double* __restrict__ smooth_slots,
                                int N, int E, float* __restrict__ out)
{
    double smooth = 0.0;
    for (int i = 0; i < 64; ++i) smooth += smooth_slots[i];
    double dN = (double)N;
    double n_wall = d[5] > 1.0 ? d[5] : 1.0;
    double total = 1.0  * d[0] / (4.0 * dN)
                 + 0.1  * d[1] / dN
                 + 0.1  * d[2] / dN
                 + 0.05 * d[3] / dN
                 + 0.05 * d[4] / dN
                 + 0.05 * d[6] / n_wall
                 + 0.01 * smooth / (4.0 * (double)E)
                 + 0.02 * d[7] / n_wall;
    out[0] = (float)total;
}

// ===================== fast path =====================

// Pass 1: per-(block, bucket) counts; contiguous row writes.
__global__ __launch_bounds__(256) void count_kernel(
    const void* __restrict__ eidx, int E, int N, int NB,
    const int* __restrict__ flag, unsigned* __restrict__ counts)
{
    __shared__ unsigned hist[MAXNB];
    hist[threadIdx.x] = 0u;
    __syncthreads();
    const int is64 = *flag;
    const long long* ll = (const long long*)eidx;
    const int* ii = (const int*)eidx;
    int chunk = (E + NBLK - 1) / NBLK;
    int s = blockIdx.x * chunk;
    int eend = min(E, s + chunk);
    for (int e = s + (int)threadIdx.x; e < eend; e += 256) {
        int r = is64 ? (int)ll[e] : ii[e];
        r = min(max(r, 0), N - 1);
        atomicAdd(&hist[r >> 9], 1u);
    }
    __syncthreads();
    if (threadIdx.x < NB)
        counts[(size_t)blockIdx.x * NBP + threadIdx.x] = hist[threadIdx.x];
}

// Pass 2a: per-(group, bucket) sums; gsum TRANSPOSED: [bucket][NGRP].
__global__ __launch_bounds__(256) void group_sums_kernel(
    const unsigned* __restrict__ counts, unsigned* __restrict__ gsum, int NB)
{
    __shared__ unsigned red[4][64];
    int g = blockIdx.x;
    int b0 = blockIdx.y * 64;
    int j = threadIdx.x & 63, seg = threadIdx.x >> 6;
    int b = b0 + j;
    unsigned ssum = 0;
    if (b < NB) {
        #pragma unroll
        for (int k = 0; k < 16; ++k) {
            int row = g * GRP + seg * 16 + k;
            ssum += counts[(size_t)row * NBP + b];
        }
    }
    red[seg][j] = ssum;
    __syncthreads();
    if (seg == 0 && b < NB)
        gsum[(size_t)b * NGRP + g] = red[0][j] + red[1][j] + red[2][j] + red[3][j];
}

// Pass 2b: bucket totals (contiguous 64-u32 row reads) -> shfl block scan ->
// base; fold base into gsum so gsum[b][g] = global offset of group g.
__global__ __launch_bounds__(256) void scan_base_kernel(
    unsigned* __restrict__ gsum, unsigned* __restrict__ base, int NB)
{
    __shared__ unsigned wt[4];
    int t = threadIdx.x;
    int lane = t & 63, wv = t >> 6;
    unsigned total = 0;
    if (t < NB) {
        #pragma unroll 1
        for (int g = 0; g < NGRP; ++g) total += gsum[(size_t)t * NGRP + g];
    }
    unsigned x = total;
    #pragma unroll
    for (int off = 1; off < 64; off <<= 1) {
        unsigned y = (unsigned)__shfl_up((int)x, off, 64);
        if (lane >= off) x += y;
    }
    if (lane == 63) wt[wv] = x;
    __syncthreads();
    unsigned wadd = 0;
    for (int w = 0; w < wv; ++w) wadd += wt[w];
    unsigned incl = x + wadd;
    unsigned ex = incl - total;
    if (t < NB) {
        base[t] = ex;
        if (t == NB - 1) base[NB] = incl;
        unsigned run = ex;
        #pragma unroll 1
        for (int g = 0; g < NGRP; ++g) {
            unsigned v = gsum[(size_t)t * NGRP + g];
            gsum[(size_t)t * NGRP + g] = run;
            run += v;
        }
    }
}

// Pass 2c: within-group scan; counts[blk][b] -> final global write offset.
__global__ __launch_bounds__(256) void local_scan_kernel(
    unsigned* __restrict__ counts, const unsigned* __restrict__ gsum, int NB)
{
    __shared__ unsigned segs[4][64];
    int g = blockIdx.x;
    int b0 = blockIdx.y * 64;
    int j = threadIdx.x & 63, seg = threadIdx.x >> 6;
    int b = b0 + j;
    unsigned v[16];
    unsigned ssum = 0;
    if (b < NB) {
        #pragma unroll
        for (int k = 0; k < 16; ++k) {
            int row = g * GRP + seg * 16 + k;
            v[k] = counts[(size_t)row * NBP + b];
            ssum += v[k];
        }
    }
    segs[seg][j] = ssum;
    __syncthreads();
    if (b < NB) {
        unsigned carry = gsum[(size_t)b * NGRP + g];
        for (int s_ = 0; s_ < seg; ++s_) carry += segs[s_][j];
        #pragma unroll
        for (int k = 0; k < 16; ++k) {
            int row = g * GRP + seg * 16 + k;
            counts[(size_t)row * NBP + b] = carry;
            carry += v[k];
        }
    }
}

// Pass 3: pure-streaming scatter. Payload = {col|rl<<17, half2(dx,dy)} 8 B.
__global__ __launch_bounds__(256) void scatter_kernel(
    const void* __restrict__ eidx, const float2* __restrict__ eattr,
    int E, int N, int NB, const int* __restrict__ flag,
    const unsigned* __restrict__ localoff /* scanned counts [blk][NBP] */,
    uint2* __restrict__ vals)
{
    __shared__ unsigned hist[MAXNB];    // -> scan0
    __shared__ unsigned cur[MAXNB];
    __shared__ unsigned gb2[MAXNB];
    __shared__ uint2 pl[CMAX];
    __shared__ unsigned char bb[CMAX];
    __shared__ unsigned wt[4];

    const int t = threadIdx.x;
    const int blk = blockIdx.x;
    const int lane = t & 63, wv = t >> 6;
    const int is64 = *flag;
    const long long* ll = (const long long*)eidx;
    const int* ii = (const int*)eidx;
    const int chunk = (E + NBLK - 1) / NBLK;
    const int s = blk * chunk;
    const int Cb = min(chunk, E - s);

    hist[t] = 0u;
    __syncthreads();

    // Phase A: rows -> regs, histogram.
    unsigned rr[KMAX];
    #pragma unroll
    for (int k = 0; k < KMAX; ++k) {
        int i = k * 256 + t;
        if (i < Cb) {
            int r = is64 ? (int)ll[s + i] : ii[s + i];
            r = min(max(r, 0), N - 1);
            rr[k] = (unsigned)r;
            atomicAdd(&hist[r >> 9], 1u);
        } else rr[k] = 0xFFFFFFFFu;
    }
    if (t < NB) gb2[t] = localoff[(size_t)blk * NBP + t];
    __syncthreads();

    // exclusive shfl-scan of hist[0..255], 1 bin/thread, 2 barriers
    unsigned h = hist[t];
    unsigned x = h;
    #pragma unroll
    for (int off = 1; off < 64; off <<= 1) {
        unsigned y = (unsigned)__shfl_up((int)x, off, 64);
        if (lane >= off) x += y;
    }
    if (lane == 63) wt[wv] = x;
    __syncthreads();
    unsigned wadd = 0;
    for (int w = 0; w < wv; ++w) wadd += wt[w];
    unsigned ex = x + wadd - h;
    hist[t] = ex;
    cur[t] = ex;
    __syncthreads();
    if (t < NB) gb2[t] -= hist[t];
    __syncthreads();

    // Phase B: sequential coalesced reads, pack payload, stage to sorted slot.
    #pragma unroll
    for (int k = 0; k < KMAX; ++k) {
        int i = k * 256 + t;
        if (i >= Cb) break;
        int e = s + i;
        unsigned r = rr[k];
        unsigned b = r >> 9;
        unsigned rl = r & (NPB - 1);
        int c = is64 ? (int)ll[(long long)E + e] : ii[E + e];
        c = min(max(c, 0), N - 1);
        float2 dxy = eattr[e];
        unsigned pk = (unsigned)c | (rl << 17);
        unsigned pos = atomicAdd(&cur[b], 1u);
        pl[pos] = make_uint2(pk, packh2(dxy.x, dxy.y));
        bb[pos] = (unsigned char)b;
    }
    __syncthreads();

    // Phase C: coalesced stores of sorted slots.
    #pragma unroll
    for (int k = 0; k < KMAX; ++k) {
        int p = k * 256 + t;
        if (p >= Cb) break;
        unsigned b = bb[p];
        vals[gb2[b] + (unsigned)p] = pl[p];
    }
}

// Pass 4: gather + physics + in-LDS counting sort + register run-sum.
// NO accumulation atomics in LDS; atomic merge into g[5][N] (2 MB, zeroed).
__global__ __launch_bounds__(512) void accum_kernel(
    const uint2* __restrict__ vals, const unsigned* __restrict__ base,
    const float4* __restrict__ pred, int N,
    float* __restrict__ g /* [5][N] */, double* __restrict__ smooth_slots)
{
    __shared__ uint2 pl[CH];           // 16 KB sorted bf16x4 physics
    __shared__ uint2 ph[NPB];          // 4 KB fp16 pred of bucket rows
    __shared__ unsigned hist[NPB];     // 2 KB
    __shared__ unsigned cur[NPB];      // 2 KB
    __shared__ unsigned wt[8];
    __shared__ double sm[8];

    const int b = blockIdx.x;
    const int t = threadIdx.x;
    const int wv = t >> 6, lane = t & 63;
    const int n0 = b * NPB;

    {   // stage bucket's pred rows as fp16
        int n = n0 + t;
        float4 p = (n < N) ? pred[n] : make_float4(0.f, 0.f, 0.f, 0.f);
        ph[t] = make_uint2(packh2(p.x, p.y), packh2(p.z, p.w));
    }

    unsigned s0 = base[b], e0 = base[b + 1];
    unsigned len = e0 - s0;
    unsigned s = s0 + (unsigned)(((unsigned long long)len * blockIdx.y) / SPLIT);
    unsigned e = s0 + (unsigned)(((unsigned long long)len * (blockIdx.y + 1)) / SPLIT);

    float cnt = 0, sdiv = 0, smx = 0, smy = 0, sstr = 0;
    double smooth = 0.0;

    for (unsigned cs = s; cs < e; cs += CH) {
        const int n = (int)min((unsigned)CH, e - cs);
        hist[t] = 0u;
        __syncthreads();

        // (a) coalesced payload read -> registers + histogram
        uint2 vv[4];
        #pragma unroll
        for (int k = 0; k < 4; ++k) {
            int i = k * 512 + t;
            if (i < n) {
                vv[k] = vals[cs + i];
                atomicAdd(&hist[(vv[k].x >> 17) & (NPB - 1)], 1u);
            } else vv[k].x = 0xFFFFFFFFu;
        }
        __syncthreads();

        // (b) exclusive scan of 512 bins (1/thread): shfl + wave totals
        unsigned v = hist[t];
        unsigned x = v;
        #pragma unroll
        for (int off = 1; off < 64; off <<= 1) {
            unsigned y = (unsigned)__shfl_up((int)x, off, 64);
            if (lane >= off) x += y;
        }
        if (lane == 63) wt[wv] = x;
        __syncthreads();
        unsigned wadd = 0;
        for (int w = 0; w < wv; ++w) wadd += wt[w];
        unsigned incl = x + wadd;
        unsigned ex0 = incl - v;
        cur[t] = ex0;
        cnt += (float)v;               // count from histogram — no atomic
        __syncthreads();

        // (c) gather + physics + scatter to sorted LDS slot
        #pragma unroll
        for (int k = 0; k < 4; ++k) {
            int i = k * 512 + t;
            if (i >= n) break;
            unsigned pk = vv[k].x;
            int col = (int)(pk & 0x1FFFFu);
            unsigned rl = (pk >> 17) & (NPB - 1);
            float2 dxy = unpackh2(vv[k].y);
            float4 pc = pred[col];
            uint2 pru = ph[rl];
            float2 pxy = unpackh2(pru.x);
            float2 pzw = unpackh2(pru.y);
            float du = pc.x - pxy.x, dv = pc.y - pxy.y;
            float dp = pc.z - pzw.x, dn = pc.w - pzw.y;
            float rx  = 1.0f / (dxy.x + EPS);
            float ry  = 1.0f / (dxy.y + EPS);
            float rx2 = 1.0f / (dxy.x * dxy.x + EPS);
            float ry2 = 1.0f / (dxy.y * dxy.y + EPS);
            float du_dx = du * rx, du_dy = du * ry;
            float dv_dx = dv * rx, dv_dy = dv * ry;
            float nu_eff = NU_MOL + pzw.y;
            float sh = du_dy + dv_dx;
            float div_e = du_dx + dv_dy;
            float mx_e  = dp * rx + nu_eff * du * rx2;
            float my_e  = dp * ry + nu_eff * dv * ry2;
            float str_e = 2.0f * (du_dx * du_dx + dv_dy * dv_dy) + sh * sh;
            unsigned pos = atomicAdd(&cur[rl], 1u);
            pl[pos] = make_uint2(bf16rne(div_e) | (bf16rne(mx_e) << 16),
                                 bf16rne(my_e) | (bf16rne(str_e) << 16));
            smooth += (double)(du * du + dv * dv + dp * dp + dn * dn);
        }
        __syncthreads();

        // (d) register run-sum over contiguous run [ex0, incl) — no atomics
        for (unsigned i = ex0; i < incl; ++i) {
            uint2 pv = pl[i];
            sdiv += bf16dec(pv.x & 0xFFFFu);
            smx  += bf16dec(pv.x >> 16);
            smy  += bf16dec(pv.y & 0xFFFFu);
            sstr += bf16dec(pv.y >> 16);
        }
        __syncthreads();
    }

    // merge partials into global node arrays (coalesced low-contention atomics)
    {
        int n = n0 + t;
        if (n < N) {
            atomicAdd(&g[0 * (size_t)N + n], cnt);
            atomicAdd(&g[1 * (size_t)N + n], sdiv);
            atomicAdd(&g[2 * (size_t)N + n], smx);
            atomicAdd(&g[3 * (size_t)N + n], smy);
            atomicAdd(&g[4 * (size_t)N + n], sstr);
        }
    }

    for (int off = 32; off > 0; off >>= 1)
        smooth += __shfl_down(smooth, off);
    if (lane == 0) sm[wv] = smooth;
    __syncthreads();
    if (t == 0) {
        double tot = 0;
        #pragma unroll
        for (int w = 0; w < 8; ++w) tot += sm[w];
        atomicAdd(&smooth_slots[(b * SPLIT + blockIdx.y) & 63], tot);
    }
}

// Pass 5: node losses from g[5][N] + fused finalize (arrival counter).
__global__ __launch_bounds__(256) void node_final_kernel(
    const float* __restrict__ g, const float4* __restrict__ pred,
    const float4* __restrict__ tgt, const unsigned char* __restrict__ wall,
    int N, int E, double* __restrict__ d,
    const double* __restrict__ smooth_slots, unsigned* __restrict__ counter,
    float* __restrict__ out)
{
    int i = blockIdx.x * 256 + threadIdx.x;
    double v0 = 0, v1 = 0, v2 = 0, v3 = 0, v4 = 0, v5 = 0, v6 = 0, v7 = 0;
    if (i < N) {
        float cnt  = g[0 * (size_t)N + i];
        float inv = 1.0f / fmaxf(cnt, 1.0f);
        float div = g[1 * (size_t)N + i] * inv;
        float mx  = g[2 * (size_t)N + i] * inv;
        float my  = g[3 * (size_t)N + i] * inv;
        float sn  = g[4 * (size_t)N + i] * inv;
        float4 p = pred[i];
        float4 tg = tgt[i];
        float prod = p.w * sn;
        float m = wall[i] ? 1.0f : 0.0f;
        float e0 = p.x - tg.x, e1 = p.y - tg.y, e2 = p.z - tg.z, e3 = p.w - tg.w;
        float uv = p.x * p.x + p.y * p.y;
        v0 = (double)(e0 * e0 + e1 * e1 + e2 * e2 + e3 * e3);
        v1 = (double)div * (double)div;
        v2 = (double)mx * (double)mx + (double)my * (double)my;
        v3 = (double)prod * (double)prod;
        v4 = (double)p.w * (double)p.w;
        v5 = (double)m;
        v6 = (double)(m * uv);
        v7 = (double)(m * (uv + p.w * p.w));
    }
    for (int off = 32; off > 0; off >>= 1) {
        v0 += __shfl_down(v0, off); v1 += __shfl_down(v1, off);
        v2 += __shfl_down(v2, off); v3 += __shfl_down(v3, off);
        v4 += __shfl_down(v4, off); v5 += __shfl_down(v5, off);
        v6 += __shfl_down(v6, off); v7 += __shfl_down(v7, off);
    }
    __shared__ double sm[4][8];
    __shared__ int is_last;
    int lane = threadIdx.x & 63, wv = threadIdx.x >> 6;
    if (lane == 0) {
        sm[wv][0] = v0; sm[wv][1] = v1; sm[wv][2] = v2; sm[wv][3] = v3;
        sm[wv][4] = v4; sm[wv][5] = v5; sm[wv][6] = v6; sm[wv][7] = v7;
    }
    __syncthreads();
    if (threadIdx.x < 8) {
        int q = threadIdx.x;
        atomicAdd(&d[q], sm[0][q] + sm[1][q] + sm[2][q] + sm[3][q]);
    }
    __threadfence();
    __syncthreads();
    if (threadIdx.x == 0) {
        unsigned prev = atomicAdd(counter, 1u);
        is_last = (prev == gridDim.x - 1) ? 1 : 0;
    }
    __syncthreads();
    if (is_last && threadIdx.x == 0) {
        __threadfence();
        double dd[8];
        #pragma unroll
        for (int q = 0; q < 8; ++q) dd[q] = atomicAdd(&d[q], 0.0);  // coherent read
        double smooth = 0.0;
        for (int k = 0; k < 64; ++k) smooth += smooth_slots[k];
        double dN = (double)N;
        double n_wall = dd[5] > 1.0 ? dd[5] : 1.0;
        double total = 1.0  * dd[0] / (4.0 * dN)
                     + 0.1  * dd[1] / dN
                     + 0.1  * dd[2] / dN
                     + 0.05 * dd[3] / dN
                     + 0.05 * dd[4] / dN
                     + 0.05 * dd[6] / n_wall
                     + 0.01 * smooth / (4.0 * (double)E)
                     + 0.02 * dd[7] / n_wall;
        out[0] = (float)total;
    }
}

// ===================== fallback path (R1-style, known-correct) =====================

__global__ __launch_bounds__(256) void edge_kernel(
    const void* __restrict__ eidx, const float2* __restrict__ eattr,
    const float4* __restrict__ pred, int E, int N, const int* __restrict__ flag,
    float* __restrict__ a_cnt, float* __restrict__ a_div,
    float* __restrict__ a_mx, float* __restrict__ a_my,
    float* __restrict__ a_str, double* __restrict__ smooth_slots)
{
    const int is64 = *flag;
    const long long* ll = (const long long*)eidx;
    const int* ii = (const int*)eidx;
    double smooth = 0.0;
    const int stride = gridDim.x * blockDim.x;
    for (int e = blockIdx.x * blockDim.x + threadIdx.x; e < E; e += stride) {
        int row, col;
        if (is64) { row = (int)ll[e]; col = (int)ll[(long long)E + e]; }
        else      { row = ii[e];      col = ii[E + e]; }
        row = min(max(row, 0), N - 1);
        col = min(max(col, 0), N - 1);
        float2 dxy = eattr[e];
        float4 pr = pred[row];
        float4 pc = pred[col];
        float du = pc.x - pr.x, dv = pc.y - pr.y;
        float dp = pc.z - pr.z, dn = pc.w - pr.w;
        float rx  = 1.0f / (dxy.x + EPS);
        float ry  = 1.0f / (dxy.y + EPS);
        float rx2 = 1.0f / (dxy.x * dxy.x + EPS);
        float ry2 = 1.0f / (dxy.y * dxy.y + EPS);
        float du_dx = du * rx, du_dy = du * ry;
        float dv_dx = dv * rx, dv_dy = dv * ry;
        float nu_eff = NU_MOL + pr.w;
        atomicAdd(&a_cnt[row], 1.0f);
        atomicAdd(&a_div[row], du_dx + dv_dy);
        atomicAdd(&a_mx[row], dp * rx + nu_eff * du * rx2);
        atomicAdd(&a_my[row], dp * ry + nu_eff * dv * ry2);
        float sh = du_dy + dv_dx;
        atomicAdd(&a_str[row], 2.0f * (du_dx * du_dx + dv_dy * dv_dy) + sh * sh);
        smooth += (double)(du * du + dv * dv + dp * dp + dn * dn);
    }
    for (int off = 32; off > 0; off >>= 1)
        smooth += __shfl_down(smooth, off);
    __shared__ double sm[4];
    int lane = threadIdx.x & 63, wv = threadIdx.x >> 6;
    if (lane == 0) sm[wv] = smooth;
    __syncthreads();
    if (threadIdx.x == 0)
        atomicAdd(&smooth_slots[blockIdx.x & 63], sm[0] + sm[1] + sm[2] + sm[3]);
}

__global__ __launch_bounds__(256) void node_kernel(
    const float4* __restrict__ pred, const float4* __restrict__ tgt,
    const unsigned char* __restrict__ wall, int N,
    const float* __restrict__ a_cnt, const float* __restrict__ a_div,
    const float* __restrict__ a_mx, const float* __restrict__ a_my,
    const float* __restrict__ a_str, double* __restrict__ d)
{
    int i = blockIdx.x * blockDim.x + threadIdx.x;
    double v0 = 0, v1 = 0, v2 = 0, v3 = 0, v4 = 0, v5 = 0, v6 = 0, v7 = 0;
    if (i < N) {
        float4 p = pred[i];
        float4 t = tgt[i];
        float inv = 1.0f / fmaxf(a_cnt[i], 1.0f);
        float div = a_div[i] * inv;
        float mx = a_mx[i] * inv, my = a_my[i] * inv;
        float sn = a_str[i] * inv;
        float prod = p.w * sn;
        float m = wall[i] ? 1.0f : 0.0f;
        float e0 = p.x - t.x, e1 = p.y - t.y, e2 = p.z - t.z, e3 = p.w - t.w;
        float uv = p.x * p.x + p.y * p.y;
        v0 = (double)(e0 * e0 + e1 * e1 + e2 * e2 + e3 * e3);
        v1 = (double)div * (double)div;
        v2 = (double)mx * (double)mx + (double)my * (double)my;
        v3 = (double)prod * (double)prod;
        v4 = (double)p.w * (double)p.w;
        v5 = (double)m;
        v6 = (double)(m * uv);
        v7 = (double)(m * (uv + p.w * p.w));
    }
    for (int off = 32; off > 0; off >>= 1) {
        v0 += __shfl_down(v0, off); v1 += __shfl_down(v1, off);
        v2 += __shfl_down(v2, off); v3 += __shfl_down(v3, off);
        v4 += __shfl_down(v4, off); v5 += __shfl_down(v5, off);
        v6 += __shfl_down(v6, off); v7 += __shfl_down(v7, off);
    }
    __shared__ double sm[4][8];
    int lane = threadIdx.x & 63, wv = threadIdx.x >> 6;
    if (lane == 0) {
        sm[wv][0] = v0; sm[wv][1] = v1; sm[wv][2] = v2; sm[wv][3] = v3;
        sm[wv][4] = v4; sm[wv][5] = v5; sm[wv][6] = v6; sm[wv][7] = v7;
    }
    __syncthreads();
    if (threadIdx.x < 8) {
        int q = threadIdx.x;
        atomicAdd(&d[q], sm[0][q] + sm[1][q] + sm[2][q] + sm[3][q]);
    }
}

// ===================== launch =====================

extern "C" void kernel_launch(void* const* d_in, const int* in_sizes, int n_in,
                              void* d_out, int out_size, void* d_ws, size_t ws_size,
                              hipStream_t stream) {
    const float4* pred = (const float4*)d_in[0];
    const float4* tgt  = (const float4*)d_in[1];
    const float2* eattr = (const float2*)d_in[2];
    const void* eidx = d_in[3];
    const unsigned char* wall = (const unsigned char*)d_in[4];
    int N = in_sizes[0] / 4;
    int E = in_sizes[2] / 2;
    int NB = (N + NPB - 1) / NPB;
    int chunk = (E + NBLK - 1) / NBLK;
    int ntiles = (NB + 63) / 64;

    char* ws = (char*)d_ws;
    double* d = (double*)ws;                 // 8 scalars
    double* smooth_slots = d + 8;            // 64 slots
    int* flag = (int*)(ws + 576);
    unsigned* counter = (unsigned*)(ws + 580);

    size_t off = 1024;
    float* g        = (float*)(ws + off);     off += (size_t)5 * N * 4;  // zeroed
    unsigned* counts = (unsigned*)(ws + off); off += (size_t)NBLK * NBP * 4;
    unsigned* gsum   = (unsigned*)(ws + off); off += (size_t)MAXNB * NGRP * 4;
    unsigned* base   = (unsigned*)(ws + off); off += (size_t)(NB + 1) * 4;
    off = (off + 15) & ~(size_t)15;
    uint2* vals      = (uint2*)(ws + off);    off += (size_t)E * 8;
    size_t need_fast = off;

    bool fast = (NB <= MAXNB) && (N <= 131072) && (chunk <= CMAX) &&
                (ws_size >= need_fast);

    if (fast) {
        hipMemsetAsync(d_ws, 0, 1024 + (size_t)5 * N * 4, stream);
        detect_idx_dtype<<<1, 1, 0, stream>>>(eidx, N, flag);
        count_kernel<<<NBLK, 256, 0, stream>>>(eidx, E, N, NB, flag, counts);
        group_sums_kernel<<<dim3(NGRP, ntiles), 256, 0, stream>>>(counts, gsum, NB);
        scan_base_kernel<<<1, 256, 0, stream>>>(gsum, base, NB);
        local_scan_kernel<<<dim3(NGRP, ntiles), 256, 0, stream>>>(counts, gsum, NB);
        scatter_kernel<<<NBLK, 256, 0, stream>>>(eidx, eattr, E, N, NB, flag,
                                                 counts, vals);
        accum_kernel<<<dim3(NB, SPLIT), 512, 0, stream>>>(vals, base, pred, N,
                                                          g, smooth_slots);
        node_final_kernel<<<(N + 255) / 256, 256, 0, stream>>>(g, pred, tgt, wall,
                                                               N, E, d,
                                                               smooth_slots, counter,
                                                               (float*)d_out);
    } else {
        float* arrays = (float*)(ws + 1024);
        float* a_cnt = arrays + (size_t)0 * N;
        float* a_div = arrays + (size_t)1 * N;
        float* a_mx  = arrays + (size_t)2 * N;
        float* a_my  = arrays + (size_t)3 * N;
        float* a_str = arrays + (size_t)4 * N;
        size_t zbytes = 1024 + (size_t)5 * N * sizeof(float);
        hipMemsetAsync(d_ws, 0, zbytes, stream);
        detect_idx_dtype<<<1, 1, 0, stream>>>(eidx, N, flag);
        edge_kernel<<<4096, 256, 0, stream>>>(eidx, eattr, pred, E, N, flag,
                                              a_cnt, a_div, a_mx, a_my, a_str,
                                              smooth_slots);
        node_kernel<<<(N + 255) / 256, 256, 0, stream>>>(pred, tgt, wall, N,
                                                         a_cnt, a_div, a_mx, a_my,
                                                         a_str, d);
        finalize_kernel<<<1, 1, 0, stream>>>(d, smooth_slots, N, E, (float*)d_out);
    }
}

// Round 13
// 268.958 us; speedup vs baseline: 1.0815x; 1.0222x over previous
//
#include <hip/hip_runtime.h>
#include <hip/hip_fp16.h>

#define EPS 1e-8f
#define NU_MOL 1.5e-5f
#define NPB 512            // nodes per bucket (9-bit rl)
#define MAXNB 256          // max buckets (N <= 131072, 17-bit col pack)
#define NBLK 4096          // edge-chunk blocks for scatter
#define CMAX 1664          // max edges per block chunk (E <= 6.81M)
#define KMAX 7             // ceil(CMAX/256)
#define CH 2048            // accum chunk entries
#define NSUB 8             // sub-arenas per bucket (reservation contention /8)

// ===================== helpers =====================

union U32H2 { unsigned u; __half2 h; };

__device__ inline unsigned packh2(float a, float b) {
    U32H2 x; x.h = __halves2half2(__float2half_rn(a), __float2half_rn(b));
    return x.u;
}
__device__ inline float2 unpackh2(unsigned u) {
    U32H2 x; x.u = u;
    return make_float2(__low2float(x.h), __high2float(x.h));
}
__device__ inline unsigned bf16rne(float f) {
    unsigned u = __float_as_uint(f);
    u += 0x7FFFu + ((u >> 16) & 1u);
    return u >> 16;
}
__device__ inline float bf16dec(unsigned h) {
    return __uint_as_float(h << 16);
}

// ===================== common =====================

__global__ void detect_idx_dtype(const void* eidx, int N, int* flag) {
    const long long* ll = (const long long*)eidx;
    int is64 = 1;
    for (int i = 0; i < 16; ++i) {
        long long v = ll[i];
        if (v < 0 || v >= (long long)N) { is64 = 0; break; }
    }
    *flag = is64;
}

__global__ void finalize_kernel(const double* __restrict__ d,
                                const double* __restrict__ smooth_slots,
                                int N, int E, float* __restrict__ out)
{
    double smooth = 0.0;
    for (int i = 0; i < 64; ++i) smooth += smooth_slots[i];
    double dN = (double)N;
    double n_wall = d[5] > 1.0 ? d[5] : 1.0;
    double total = 1.0  * d[0] / (4.0 * dN)
                 + 0.1  * d[1] / dN
                 + 0.1  * d[2] / dN
                 + 0.05 * d[3] / dN
                 + 0.05 * d[4] / dN
                 + 0.05 * d[6] / n_wall
                 + 0.01 * smooth / (4.0 * (double)E)
                 + 0.02 * d[7] / n_wall;
    out[0] = (float)total;
}

// ===================== fast path =====================

// Pass 1: streaming scatter with SUB-ARENA atomic reservation.
// Bucket b, sub-arena s region: vals[(b*NSUB+s)*subcap ...). Each block
// reserves its per-bucket run in sub-arena (blk & 7) with ONE global atomic
// per nonempty bucket; chain depth per cursor = NBLK/NSUB = 512 (~7 us).
// No count kernel, no prefix-sum pipeline. gcur[b*NSUB+s] ends as the
// sub-arena fill count (order-independent; accum's sort doesn't need order).
__global__ __launch_bounds__(256) void scatter_kernel(
    const void* __restrict__ eidx, const float2* __restrict__ eattr,
    int E, int N, int NB, int subcap, const int* __restrict__ flag,
    unsigned* __restrict__ gcur, uint2* __restrict__ vals)
{
    __shared__ unsigned hist[MAXNB];    // histogram -> scan0
    __shared__ unsigned cur[MAXNB];
    __shared__ unsigned gb2[MAXNB];
    __shared__ uint2 pl[CMAX];
    __shared__ unsigned char bb[CMAX];
    __shared__ unsigned wt[4];

    const int t = threadIdx.x;
    const int blk = blockIdx.x;
    const int lane = t & 63, wv = t >> 6;
    const int sub = blk & (NSUB - 1);
    const int is64 = *flag;
    const long long* ll = (const long long*)eidx;
    const int* ii = (const int*)eidx;
    const int chunk = (E + NBLK - 1) / NBLK;
    const int s = blk * chunk;
    const int Cb = min(chunk, E - s);

    hist[t] = 0u;
    __syncthreads();

    // Phase A: rows -> regs, histogram.
    unsigned rr[KMAX];
    #pragma unroll
    for (int k = 0; k < KMAX; ++k) {
        int i = k * 256 + t;
        if (i < Cb) {
            int r = is64 ? (int)ll[s + i] : ii[s + i];
            r = min(max(r, 0), N - 1);
            rr[k] = (unsigned)r;
            atomicAdd(&hist[r >> 9], 1u);
        } else rr[k] = 0xFFFFFFFFu;
    }
    __syncthreads();

    // Reserve sub-arena runs: one global atomic per nonempty bucket.
    unsigned h = hist[t];
    unsigned rs = 0u;
    if (t < NB && h > 0u) {
        rs = atomicAdd(&gcur[t * NSUB + sub], h);
        // clamp only for degenerate/adversarial inputs (cap is ~30 sigma)
        if (rs + h > (unsigned)subcap)
            rs = (h <= (unsigned)subcap) ? (unsigned)subcap - h : 0u;
    }

    // exclusive shfl-scan of hist[0..255] -> scan0
    unsigned x = h;
    #pragma unroll
    for (int off = 1; off < 64; off <<= 1) {
        unsigned y = (unsigned)__shfl_up((int)x, off, 64);
        if (lane >= off) x += y;
    }
    if (lane == 63) wt[wv] = x;
    __syncthreads();
    unsigned wadd = 0;
    for (int w = 0; w < wv; ++w) wadd += wt[w];
    unsigned ex = x + wadd - h;
    hist[t] = ex;
    cur[t] = ex;
    gb2[t] = (unsigned)(t * NSUB + sub) * (unsigned)subcap + rs - ex;
    __syncthreads();

    // Phase B: sequential coalesced reads, pack payload, stage to sorted slot.
    #pragma unroll
    for (int k = 0; k < KMAX; ++k) {
        int i = k * 256 + t;
        if (i >= Cb) break;
        int e = s + i;
        unsigned r = rr[k];
        unsigned b = r >> 9;
        unsigned rl = r & (NPB - 1);
        int c = is64 ? (int)ll[(long long)E + e] : ii[E + e];
        c = min(max(c, 0), N - 1);
        float2 dxy = eattr[e];
        unsigned pk = (unsigned)c | (rl << 17);
        unsigned pos = atomicAdd(&cur[b], 1u);
        pl[pos] = make_uint2(pk, packh2(dxy.x, dxy.y));
        bb[pos] = (unsigned char)b;
    }
    __syncthreads();

    // Phase C: coalesced stores of sorted slots into reserved runs.
    #pragma unroll
    for (int k = 0; k < KMAX; ++k) {
        int p = k * 256 + t;
        if (p >= Cb) break;
        unsigned b = bb[p];
        vals[gb2[b] + (unsigned)p] = pl[p];
    }
}

// Pass 2: gather + physics + in-LDS counting sort + register run-sum.
// One block per (bucket, sub-arena); atomic merge into g[5][N] (2 MB, zeroed).
__global__ __launch_bounds__(512) void accum_kernel(
    const uint2* __restrict__ vals, const unsigned* __restrict__ gcur, int subcap,
    const float4* __restrict__ pred, int N,
    float* __restrict__ g /* [5][N] */, double* __restrict__ smooth_slots)
{
    __shared__ uint2 pl[CH];           // 16 KB sorted bf16x4 physics
    __shared__ uint2 ph[NPB];          // 4 KB fp16 pred of bucket rows
    __shared__ unsigned hist[NPB];     // 2 KB
    __shared__ unsigned cur[NPB];      // 2 KB
    __shared__ unsigned wt[8];
    __shared__ double sm[8];

    const int b = blockIdx.x;
    const int y = blockIdx.y;
    const int t = threadIdx.x;
    const int wv = t >> 6, lane = t & 63;
    const int n0 = b * NPB;

    {   // stage bucket's pred rows as fp16
        int n = n0 + t;
        float4 p = (n < N) ? pred[n] : make_float4(0.f, 0.f, 0.f, 0.f);
        ph[t] = make_uint2(packh2(p.x, p.y), packh2(p.z, p.w));
    }

    unsigned s0 = (unsigned)(b * NSUB + y) * (unsigned)subcap;
    unsigned len = min(gcur[b * NSUB + y], (unsigned)subcap);
    unsigned s = s0, e = s0 + len;

    float cnt = 0, sdiv = 0, smx = 0, smy = 0, sstr = 0;
    double smooth = 0.0;

    for (unsigned cs = s; cs < e; cs += CH) {
        const int n = (int)min((unsigned)CH, e - cs);
        hist[t] = 0u;
        __syncthreads();

        // (a) coalesced payload read -> registers + histogram
        uint2 vv[4];
        #pragma unroll
        for (int k = 0; k < 4; ++k) {
            int i = k * 512 + t;
            if (i < n) {
                vv[k] = vals[cs + i];
                atomicAdd(&hist[(vv[k].x >> 17) & (NPB - 1)], 1u);
            } else vv[k].x = 0xFFFFFFFFu;
        }
        __syncthreads();

        // (b) exclusive scan of 512 bins (1/thread): shfl + wave totals
        unsigned v = hist[t];
        unsigned x = v;
        #pragma unroll
        for (int off = 1; off < 64; off <<= 1) {
            unsigned y2 = (unsigned)__shfl_up((int)x, off, 64);
            if (lane >= off) x += y2;
        }
        if (lane == 63) wt[wv] = x;
        __syncthreads();
        unsigned wadd = 0;
        for (int w = 0; w < wv; ++w) wadd += wt[w];
        unsigned incl = x + wadd;
        unsigned ex0 = incl - v;
        cur[t] = ex0;
        cnt += (float)v;               // count from histogram — no atomic
        __syncthreads();

        // (c) gather + physics + scatter to sorted LDS slot
        #pragma unroll
        for (int k = 0; k < 4; ++k) {
            int i = k * 512 + t;
            if (i >= n) break;
            unsigned pk = vv[k].x;
            int col = (int)(pk & 0x1FFFFu);
            unsigned rl = (pk >> 17) & (NPB - 1);
            float2 dxy = unpackh2(vv[k].y);
            float4 pc = pred[col];
            uint2 pru = ph[rl];
            float2 pxy = unpackh2(pru.x);
            float2 pzw = unpackh2(pru.y);
            float du = pc.x - pxy.x, dv = pc.y - pxy.y;
            float dp = pc.z - pzw.x, dn = pc.w - pzw.y;
            float rx  = 1.0f / (dxy.x + EPS);
            float ry  = 1.0f / (dxy.y + EPS);
            float rx2 = 1.0f / (dxy.x * dxy.x + EPS);
            float ry2 = 1.0f / (dxy.y * dxy.y + EPS);
            float du_dx = du * rx, du_dy = du * ry;
            float dv_dx = dv * rx, dv_dy = dv * ry;
            float nu_eff = NU_MOL + pzw.y;
            float sh = du_dy + dv_dx;
            float div_e = du_dx + dv_dy;
            float mx_e  = dp * rx + nu_eff * du * rx2;
            float my_e  = dp * ry + nu_eff * dv * ry2;
            float str_e = 2.0f * (du_dx * du_dx + dv_dy * dv_dy) + sh * sh;
            unsigned pos = atomicAdd(&cur[rl], 1u);
            pl[pos] = make_uint2(bf16rne(div_e) | (bf16rne(mx_e) << 16),
                                 bf16rne(my_e) | (bf16rne(str_e) << 16));
            smooth += (double)(du * du + dv * dv + dp * dp + dn * dn);
        }
        __syncthreads();

        // (d) register run-sum over contiguous run [ex0, incl) — no atomics
        for (unsigned i = ex0; i < incl; ++i) {
            uint2 pv = pl[i];
            sdiv += bf16dec(pv.x & 0xFFFFu);
            smx  += bf16dec(pv.x >> 16);
            smy  += bf16dec(pv.y & 0xFFFFu);
            sstr += bf16dec(pv.y >> 16);
        }
        __syncthreads();
    }

    // merge partials into global node arrays (coalesced low-contention atomics)
    {
        int n = n0 + t;
        if (n < N) {
            atomicAdd(&g[0 * (size_t)N + n], cnt);
            atomicAdd(&g[1 * (size_t)N + n], sdiv);
            atomicAdd(&g[2 * (size_t)N + n], smx);
            atomicAdd(&g[3 * (size_t)N + n], smy);
            atomicAdd(&g[4 * (size_t)N + n], sstr);
        }
    }

    for (int off = 32; off > 0; off >>= 1)
        smooth += __shfl_down(smooth, off);
    if (lane == 0) sm[wv] = smooth;
    __syncthreads();
    if (t == 0) {
        double tot = 0;
        #pragma unroll
        for (int w = 0; w < 8; ++w) tot += sm[w];
        atomicAdd(&smooth_slots[(b * NSUB + y) & 63], tot);
    }
}

// Pass 3: node losses from g[5][N] (plain; finalize is a separate kernel —
// per-block __threadfence finalize measured ~+30us across R10-R12).
__global__ __launch_bounds__(256) void node_final_kernel(
    const float* __restrict__ g, const float4* __restrict__ pred,
    const float4* __restrict__ tgt, const unsigned char* __restrict__ wall,
    int N, double* __restrict__ d)
{
    int i = blockIdx.x * 256 + threadIdx.x;
    double v0 = 0, v1 = 0, v2 = 0, v3 = 0, v4 = 0, v5 = 0, v6 = 0, v7 = 0;
    if (i < N) {
        float cnt  = g[0 * (size_t)N + i];
        float inv = 1.0f / fmaxf(cnt, 1.0f);
        float div = g[1 * (size_t)N + i] * inv;
        float mx  = g[2 * (size_t)N + i] * inv;
        float my  = g[3 * (size_t)N + i] * inv;
        float sn  = g[4 * (size_t)N + i] * inv;
        float4 p = pred[i];
        float4 tg = tgt[i];
        float prod = p.w * sn;
        float m = wall[i] ? 1.0f : 0.0f;
        float e0 = p.x - tg.x, e1 = p.y - tg.y, e2 = p.z - tg.z, e3 = p.w - tg.w;
        float uv = p.x * p.x + p.y * p.y;
        v0 = (double)(e0 * e0 + e1 * e1 + e2 * e2 + e3 * e3);
        v1 = (double)div * (double)div;
        v2 = (double)mx * (double)mx + (double)my * (double)my;
        v3 = (double)prod * (double)prod;
        v4 = (double)p.w * (double)p.w;
        v5 = (double)m;
        v6 = (double)(m * uv);
        v7 = (double)(m * (uv + p.w * p.w));
    }
    for (int off = 32; off > 0; off >>= 1) {
        v0 += __shfl_down(v0, off); v1 += __shfl_down(v1, off);
        v2 += __shfl_down(v2, off); v3 += __shfl_down(v3, off);
        v4 += __shfl_down(v4, off); v5 += __shfl_down(v5, off);
        v6 += __shfl_down(v6, off); v7 += __shfl_down(v7, off);
    }
    __shared__ double sm[4][8];
    int lane = threadIdx.x & 63, wv = threadIdx.x >> 6;
    if (lane == 0) {
        sm[wv][0] = v0; sm[wv][1] = v1; sm[wv][2] = v2; sm[wv][3] = v3;
        sm[wv][4] = v4; sm[wv][5] = v5; sm[wv][6] = v6; sm[wv][7] = v7;
    }
    __syncthreads();
    if (threadIdx.x < 8) {
        int q = threadIdx.x;
        atomicAdd(&d[q], sm[0][q] + sm[1][q] + sm[2][q] + sm[3][q]);
    }
}

// ===================== fallback path (R1-style, known-correct) =====================

__global__ __launch_bounds__(256) void edge_kernel(
    const void* __restrict__ eidx, const float2* __restrict__ eattr,
    const float4* __restrict__ pred, int E, int N, const int* __restrict__ flag,
    float* __restrict__ a_cnt, float* __restrict__ a_div,
    float* __restrict__ a_mx, float* __restrict__ a_my,
    float* __restrict__ a_str, double* __restrict__ smooth_slots)
{
    const int is64 = *flag;
    const long long* ll = (const long long*)eidx;
    const int* ii = (const int*)eidx;
    double smooth = 0.0;
    const int stride = gridDim.x * blockDim.x;
    for (int e = blockIdx.x * blockDim.x + threadIdx.x; e < E; e += stride) {
        int row, col;
        if (is64) { row = (int)ll[e]; col = (int)ll[(long long)E + e]; }
        else      { row = ii[e];      col = ii[E + e]; }
        row = min(max(row, 0), N - 1);
        col = min(max(col, 0), N - 1);
        float2 dxy = eattr[e];
        float4 pr = pred[row];
        float4 pc = pred[col];
        float du = pc.x - pr.x, dv = pc.y - pr.y;
        float dp = pc.z - pr.z, dn = pc.w - pr.w;
        float rx  = 1.0f / (dxy.x + EPS);
        float ry  = 1.0f / (dxy.y + EPS);
        float rx2 = 1.0f / (dxy.x * dxy.x + EPS);
        float ry2 = 1.0f / (dxy.y * dxy.y + EPS);
        float du_dx = du * rx, du_dy = du * ry;
        float dv_dx = dv * rx, dv_dy = dv * ry;
        float nu_eff = NU_MOL + pr.w;
        atomicAdd(&a_cnt[row], 1.0f);
        atomicAdd(&a_div[row], du_dx + dv_dy);
        atomicAdd(&a_mx[row], dp * rx + nu_eff * du * rx2);
        atomicAdd(&a_my[row], dp * ry + nu_eff * dv * ry2);
        float sh = du_dy + dv_dx;
        atomicAdd(&a_str[row], 2.0f * (du_dx * du_dx + dv_dy * dv_dy) + sh * sh);
        smooth += (double)(du * du + dv * dv + dp * dp + dn * dn);
    }
    for (int off = 32; off > 0; off >>= 1)
        smooth += __shfl_down(smooth, off);
    __shared__ double sm[4];
    int lane = threadIdx.x & 63, wv = threadIdx.x >> 6;
    if (lane == 0) sm[wv] = smooth;
    __syncthreads();
    if (threadIdx.x == 0)
        atomicAdd(&smooth_slots[blockIdx.x & 63], sm[0] + sm[1] + sm[2] + sm[3]);
}

__global__ __launch_bounds__(256) void node_kernel(
    const float4* __restrict__ pred, const float4* __restrict__ tgt,
    const unsigned char* __restrict__ wall, int N,
    const float* __restrict__ a_cnt, const float* __restrict__ a_div,
    const float* __restrict__ a_mx, const float* __restrict__ a_my,
    const float* __restrict__ a_str, double* __restrict__ d)
{
    int i = blockIdx.x * blockDim.x + threadIdx.x;
    double v0 = 0, v1 = 0, v2 = 0, v3 = 0, v4 = 0, v5 = 0, v6 = 0, v7 = 0;
    if (i < N) {
        float4 p = pred[i];
        float4 t = tgt[i];
        float inv = 1.0f / fmaxf(a_cnt[i], 1.0f);
        float div = a_div[i] * inv;
        float mx = a_mx[i] * inv, my = a_my[i] * inv;
        float sn = a_str[i] * inv;
        float prod = p.w * sn;
        float m = wall[i] ? 1.0f : 0.0f;
        float e0 = p.x - t.x, e1 = p.y - t.y, e2 = p.z - t.z, e3 = p.w - t.w;
        float uv = p.x * p.x + p.y * p.y;
        v0 = (double)(e0 * e0 + e1 * e1 + e2 * e2 + e3 * e3);
        v1 = (double)div * (double)div;
        v2 = (double)mx * (double)mx + (double)my * (double)my;
        v3 = (double)prod * (double)prod;
        v4 = (double)p.w * (double)p.w;
        v5 = (double)m;
        v6 = (double)(m * uv);
        v7 = (double)(m * (uv + p.w * p.w));
    }
    for (int off = 32; off > 0; off >>= 1) {
        v0 += __shfl_down(v0, off); v1 += __shfl_down(v1, off);
        v2 += __shfl_down(v2, off); v3 += __shfl_down(v3, off);
        v4 += __shfl_down(v4, off); v5 += __shfl_down(v5, off);
        v6 += __shfl_down(v6, off); v7 += __shfl_down(v7, off);
    }
    __shared__ double sm[4][8];
    int lane = threadIdx.x & 63, wv = threadIdx.x >> 6;
    if (lane == 0) {
        sm[wv][0] = v0; sm[wv][1] = v1; sm[wv][2] = v2; sm[wv][3] = v3;
        sm[wv][4] = v4; sm[wv][5] = v5; sm[wv][6] = v6; sm[wv][7] = v7;
    }
    __syncthreads();
    if (threadIdx.x < 8) {
        int q = threadIdx.x;
        atomicAdd(&d[q], sm[0][q] + sm[1][q] + sm[2][q] + sm[3][q]);
    }
}

// ===================== launch =====================

extern "C" void kernel_launch(void* const* d_in, const int* in_sizes, int n_in,
                              void* d_out, int out_size, void* d_ws, size_t ws_size,
                              hipStream_t stream) {
    const float4* pred = (const float4*)d_in[0];
    const float4* tgt  = (const float4*)d_in[1];
    const float2* eattr = (const float2*)d_in[2];
    const void* eidx = d_in[3];
    const unsigned char* wall = (const unsigned char*)d_in[4];
    int N = in_sizes[0] / 4;
    int E = in_sizes[2] / 2;
    int NB = (N + NPB - 1) / NPB;
    int chunk = (E + NBLK - 1) / NBLK;

    char* ws = (char*)d_ws;
    double* d = (double*)ws;                 // 8 scalars
    double* smooth_slots = d + 8;            // 64 slots
    int* flag = (int*)(ws + 576);
    unsigned* gcur = (unsigned*)(ws + 1024); // up to 2048 cursors (8 KB)

    size_t off0 = 1024 + 8192;
    float* g = (float*)(ws + off0);          // 5*N floats, zeroed
    size_t voff = off0 + (size_t)5 * N * 4;
    voff = (voff + 15) & ~(size_t)15;
    uint2* vals = (uint2*)(ws + voff);

    // sub-arena capacity: try slack 2.0x / 1.5x / 1.25x of mean fill
    long mean = ((long)E + (long)NB * NSUB - 1) / ((long)NB * NSUB);
    int subcap = 0;
    long slacks_num[3] = {2, 3, 5};
    long slacks_den[3] = {1, 2, 4};
    for (int si = 0; si < 3; ++si) {
        long sc = (mean * slacks_num[si] + slacks_den[si] - 1) / slacks_den[si];
        sc = (sc + 63) & ~63L;
        size_t need = voff + (size_t)NB * NSUB * sc * 8;
        if (ws_size >= need) { subcap = (int)sc; break; }
    }

    bool fast = (NB <= MAXNB) && (N <= 131072) && (chunk <= CMAX) && (subcap > 0);

    if (fast) {
        // zero header + cursors + g accumulators (contiguous)
        hipMemsetAsync(d_ws, 0, off0 + (size_t)5 * N * 4, stream);
        detect_idx_dtype<<<1, 1, 0, stream>>>(eidx, N, flag);
        scatter_kernel<<<NBLK, 256, 0, stream>>>(eidx, eattr, E, N, NB, subcap,
                                                 flag, gcur, vals);
        accum_kernel<<<dim3(NB, NSUB), 512, 0, stream>>>(vals, gcur, subcap,
                                                         pred, N, g, smooth_slots);
        node_final_kernel<<<(N + 255) / 256, 256, 0, stream>>>(g, pred, tgt, wall,
                                                               N, d);
        finalize_kernel<<<1, 1, 0, stream>>>(d, smooth_slots, N, E, (float*)d_out);
    } else {
        float* arrays = (float*)(ws + 1024);
        float* a_cnt = arrays + (size_t)0 * N;
        float* a_div = arrays + (size_t)1 * N;
        float* a_mx  = arrays + (size_t)2 * N;
        float* a_my  = arrays + (size_t)3 * N;
        float* a_str = arrays + (size_t)4 * N;
        size_t zbytes = 1024 + (size_t)5 * N * sizeof(float);
        hipMemsetAsync(d_ws, 0, zbytes, stream);
        detect_idx_dtype<<<1, 1, 0, stream>>>(eidx, N, flag);
        edge_kernel<<<4096, 256, 0, stream>>>(eidx, eattr, pred, E, N, flag,
                                              a_cnt, a_div, a_mx, a_my, a_str,
                                              smooth_slots);
        node_kernel<<<(N + 255) / 256, 256, 0, stream>>>(pred, tgt, wall, N,
                                                         a_cnt, a_div, a_mx, a_my,
                                                         a_str, d);
        finalize_kernel<<<1, 1, 0, stream>>>(d, smooth_slots, N, E, (float*)d_out);
    }
}

// Round 14
// 238.028 us; speedup vs baseline: 1.2220x; 1.1299x over previous
//
#include <hip/hip_runtime.h>
#include <hip/hip_fp16.h>

#define EPS 1e-8f
#define NU_MOL 1.5e-5f
#define NPB 512            // nodes per bucket (9-bit rl)
#define MAXNB 256          // max buckets (N <= 131072, 17-bit col pack)
#define NBP 256            // padded row stride of counts matrix
#define NBLK 4096          // edge-chunk blocks for count/scatter
#define CMAX 1664          // max edges per block chunk (E <= 6.81M)
#define KMAX 7             // ceil(CMAX/256)
#define CH 2048            // accum chunk entries
#define SPLIT 6            // entry-slices per bucket in accum
#define NGRP 64            // block-groups for hierarchical scan
#define GRP 64             // rows per group; NGRP*GRP == NBLK

// ===================== helpers =====================

union U32H2 { unsigned u; __half2 h; };

__device__ inline unsigned packh2(float a, float b) {
    U32H2 x; x.h = __halves2half2(__float2half_rn(a), __float2half_rn(b));
    return x.u;
}
__device__ inline float2 unpackh2(unsigned u) {
    U32H2 x; x.u = u;
    return make_float2(__low2float(x.h), __high2float(x.h));
}
__device__ inline unsigned bf16rne(float f) {
    unsigned u = __float_as_uint(f);
    u += 0x7FFFu + ((u >> 16) & 1u);
    return u >> 16;
}
__device__ inline float bf16dec(unsigned h) {
    return __uint_as_float(h << 16);
}

// ===================== common =====================

__global__ void detect_idx_dtype(const void* eidx, int N, int* flag) {
    const long long* ll = (const long long*)eidx;
    int is64 = 1;
    for (int i = 0; i < 16; ++i) {
        long long v = ll[i];
        if (v < 0 || v >= (long long)N) { is64 = 0; break; }
    }
    *flag = is64;
}

__global__ void finalize_kernel(const double* __restrict__ d,
                                const double* __restrict__ smooth_slots,
                                int N, int E, float* __restrict__ out)
{
    double smooth = 0.0;
    for (int i = 0; i < 64; ++i) smooth += smooth_slots[i];
    double dN = (double)N;
    double n_wall = d[5] > 1.0 ? d[5] : 1.0;
    double total = 1.0  * d[0] / (4.0 * dN)
                 + 0.1  * d[1] / dN
                 + 0.1  * d[2] / dN
                 + 0.05 * d[3] / dN
                 + 0.05 * d[4] / dN
                 + 0.05 * d[6] / n_wall
                 + 0.01 * smooth / (4.0 * (double)E)
                 + 0.02 * d[7] / n_wall;
    out[0] = (float)total;
}

// ===================== fast path =====================

// Pass 1: per-(block, bucket) counts; contiguous row writes.
// Dual per-wave-parity histograms halve LDS same-bank collision depth.
__global__ __launch_bounds__(256) void count_kernel(
    const void* __restrict__ eidx, int E, int N, int NB,
    const int* __restrict__ flag, unsigned* __restrict__ counts)
{
    __shared__ unsigned hist[2][MAXNB];
    hist[0][threadIdx.x] = 0u;
    hist[1][threadIdx.x] = 0u;
    __syncthreads();
    const int w = (threadIdx.x >> 6) & 1;
    const int is64 = *flag;
    const long long* ll = (const long long*)eidx;
    const int* ii = (const int*)eidx;
    int chunk = (E + NBLK - 1) / NBLK;
    int s = blockIdx.x * chunk;
    int eend = min(E, s + chunk);
    for (int e = s + (int)threadIdx.x; e < eend; e += 256) {
        int r = is64 ? (int)ll[e] : ii[e];
        r = min(max(r, 0), N - 1);
        atomicAdd(&hist[w][r >> 9], 1u);
    }
    __syncthreads();
    if (threadIdx.x < NB)
        counts[(size_t)blockIdx.x * NBP + threadIdx.x] =
            hist[0][threadIdx.x] + hist[1][threadIdx.x];
}

// Pass 2a: per-(group, bucket) sums of 64 block-rows. gsum[g][b].
__global__ __launch_bounds__(256) void group_sums_kernel(
    const unsigned* __restrict__ counts, unsigned* __restrict__ gsum, int NB)
{
    __shared__ unsigned red[4][64];
    int g = blockIdx.x;
    int b0 = blockIdx.y * 64;
    int j = threadIdx.x & 63, seg = threadIdx.x >> 6;
    int b = b0 + j;
    unsigned ssum = 0;
    if (b < NB) {
        #pragma unroll
        for (int k = 0; k < 16; ++k) {
            int row = g * GRP + seg * 16 + k;
            ssum += counts[(size_t)row * NBP + b];
        }
    }
    red[seg][j] = ssum;
    __syncthreads();
    if (seg == 0 && b < NB)
        gsum[(size_t)g * NBP + b] = red[0][j] + red[1][j] + red[2][j] + red[3][j];
}

// Pass 2b: scan over groups + bucket-totals scan -> base; folds base into gsum.
__global__ __launch_bounds__(512) void scan_base_kernel(
    unsigned* __restrict__ gsum, unsigned* __restrict__ base, int NB)
{
    __shared__ unsigned sc[512];
    int t = threadIdx.x;
    unsigned total = 0;
    if (t < NB)
        for (int g = 0; g < NGRP; ++g) total += gsum[(size_t)g * NBP + t];
    sc[t] = total; __syncthreads();
    for (int off = 1; off < 512; off <<= 1) {
        unsigned x = (t >= off) ? sc[t - off] : 0u;
        __syncthreads();
        sc[t] += x;
        __syncthreads();
    }
    unsigned ex = sc[t] - total;
    if (t < NB) {
        base[t] = ex;
        unsigned run = ex;
        for (int g = 0; g < NGRP; ++g) {
            unsigned x = gsum[(size_t)g * NBP + t];
            gsum[(size_t)g * NBP + t] = run;
            run += x;
        }
    }
    if (t == 511) base[NB] = sc[511];
}

// Pass 2c: within-group scan; counts[blk][b] -> final global write offset.
__global__ __launch_bounds__(256) void local_scan_kernel(
    unsigned* __restrict__ counts, const unsigned* __restrict__ gsum, int NB)
{
    __shared__ unsigned segs[4][64];
    int g = blockIdx.x;
    int b0 = blockIdx.y * 64;
    int j = threadIdx.x & 63, seg = threadIdx.x >> 6;
    int b = b0 + j;
    unsigned v[16];
    unsigned ssum = 0;
    if (b < NB) {
        #pragma unroll
        for (int k = 0; k < 16; ++k) {
            int row = g * GRP + seg * 16 + k;
            v[k] = counts[(size_t)row * NBP + b];
            ssum += v[k];
        }
    }
    segs[seg][j] = ssum;
    __syncthreads();
    if (b < NB) {
        unsigned carry = gsum[(size_t)g * NBP + b];
        for (int s_ = 0; s_ < seg; ++s_) carry += segs[s_][j];
        #pragma unroll
        for (int k = 0; k < 16; ++k) {
            int row = g * GRP + seg * 16 + k;
            counts[(size_t)row * NBP + b] = carry;
            carry += v[k];
        }
    }
}

// Pass 3: pure-streaming scatter. Payload = {col|rl<<17, half2(dx,dy)} 8 B.
// Dual Phase-A histograms (halve LDS collisions); shfl-scan (verified R12/13).
__global__ __launch_bounds__(256) void scatter_kernel(
    const void* __restrict__ eidx, const float2* __restrict__ eattr,
    int E, int N, int NB, const int* __restrict__ flag,
    const unsigned* __restrict__ localoff /* scanned counts [blk][NBP] */,
    uint2* __restrict__ vals)
{
    __shared__ unsigned hist[2][MAXNB];   // dual histograms -> scan0 in hist[0]
    __shared__ unsigned cur[MAXNB];
    __shared__ unsigned gb2[MAXNB];
    __shared__ uint2 pl[CMAX];
    __shared__ unsigned char bb[CMAX];
    __shared__ unsigned wt[4];

    const int t = threadIdx.x;
    const int blk = blockIdx.x;
    const int lane = t & 63, wv = t >> 6;
    const int w = wv & 1;
    const int is64 = *flag;
    const long long* ll = (const long long*)eidx;
    const int* ii = (const int*)eidx;
    const int chunk = (E + NBLK - 1) / NBLK;
    const int s = blk * chunk;
    const int Cb = min(chunk, E - s);

    hist[0][t] = 0u;
    hist[1][t] = 0u;
    __syncthreads();

    // Phase A: rows -> regs, dual histogram.
    unsigned rr[KMAX];
    #pragma unroll
    for (int k = 0; k < KMAX; ++k) {
        int i = k * 256 + t;
        if (i < Cb) {
            int r = is64 ? (int)ll[s + i] : ii[s + i];
            r = min(max(r, 0), N - 1);
            rr[k] = (unsigned)r;
            atomicAdd(&hist[w][r >> 9], 1u);
        } else rr[k] = 0xFFFFFFFFu;
    }
    if (t < NB) gb2[t] = localoff[(size_t)blk * NBP + t];
    __syncthreads();

    // merge + exclusive shfl-scan of 256 bins, 1/thread, 2 barriers
    unsigned h = hist[0][t] + hist[1][t];
    unsigned x = h;
    #pragma unroll
    for (int off = 1; off < 64; off <<= 1) {
        unsigned y = (unsigned)__shfl_up((int)x, off, 64);
        if (lane >= off) x += y;
    }
    if (lane == 63) wt[wv] = x;
    __syncthreads();
    unsigned wadd = 0;
    for (int w2 = 0; w2 < wv; ++w2) wadd += wt[w2];
    unsigned ex = x + wadd - h;
    hist[0][t] = ex;
    cur[t] = ex;
    __syncthreads();
    if (t < NB) gb2[t] -= hist[0][t];
    __syncthreads();

    // Phase B: sequential coalesced reads, pack payload, stage to sorted slot.
    #pragma unroll
    for (int k = 0; k < KMAX; ++k) {
        int i = k * 256 + t;
        if (i >= Cb) break;
        int e = s + i;
        unsigned r = rr[k];
        unsigned b = r >> 9;
        unsigned rl = r & (NPB - 1);
        int c = is64 ? (int)ll[(long long)E + e] : ii[E + e];
        c = min(max(c, 0), N - 1);
        float2 dxy = eattr[e];
        unsigned pk = (unsigned)c | (rl << 17);
        unsigned pos = atomicAdd(&cur[b], 1u);
        pl[pos] = make_uint2(pk, packh2(dxy.x, dxy.y));
        bb[pos] = (unsigned char)b;
    }
    __syncthreads();

    // Phase C: coalesced stores of sorted slots.
    #pragma unroll
    for (int k = 0; k < KMAX; ++k) {
        int p = k * 256 + t;
        if (p >= Cb) break;
        unsigned b = bb[p];
        vals[gb2[b] + (unsigned)p] = pl[p];
    }
}

// Pass 4: gather + physics + in-LDS counting sort + register run-sum.
// NO accumulation atomics in LDS; atomic merge into g[5][N] (2 MB, zeroed).
__global__ __launch_bounds__(512) void accum_kernel(
    const uint2* __restrict__ vals, const unsigned* __restrict__ base,
    const float4* __restrict__ pred, int N,
    float* __restrict__ g /* [5][N] */, double* __restrict__ smooth_slots)
{
    __shared__ uint2 pl[CH];           // 16 KB sorted bf16x4 physics
    __shared__ uint2 ph[NPB];          // 4 KB fp16 pred of bucket rows
    __shared__ unsigned hist[NPB];     // 2 KB
    __shared__ unsigned cur[NPB];      // 2 KB
    __shared__ unsigned wt[8];
    __shared__ double sm[8];

    const int b = blockIdx.x;
    const int t = threadIdx.x;
    const int wv = t >> 6, lane = t & 63;
    const int n0 = b * NPB;

    {   // stage bucket's pred rows as fp16
        int n = n0 + t;
        float4 p = (n < N) ? pred[n] : make_float4(0.f, 0.f, 0.f, 0.f);
        ph[t] = make_uint2(packh2(p.x, p.y), packh2(p.z, p.w));
    }

    unsigned s0 = base[b], e0 = base[b + 1];
    unsigned len = e0 - s0;
    unsigned s = s0 + (unsigned)(((unsigned long long)len * blockIdx.y) / SPLIT);
    unsigned e = s0 + (unsigned)(((unsigned long long)len * (blockIdx.y + 1)) / SPLIT);

    float cnt = 0, sdiv = 0, smx = 0, smy = 0, sstr = 0;
    double smooth = 0.0;

    for (unsigned cs = s; cs < e; cs += CH) {
        const int n = (int)min((unsigned)CH, e - cs);
        hist[t] = 0u;
        __syncthreads();

        // (a) coalesced payload read -> registers + histogram
        uint2 vv[4];
        #pragma unroll
        for (int k = 0; k < 4; ++k) {
            int i = k * 512 + t;
            if (i < n) {
                vv[k] = vals[cs + i];
                atomicAdd(&hist[(vv[k].x >> 17) & (NPB - 1)], 1u);
            } else vv[k].x = 0xFFFFFFFFu;
        }
        __syncthreads();

        // (b) exclusive scan of 512 bins (1/thread): shfl + wave totals
        unsigned v = hist[t];
        unsigned x = v;
        #pragma unroll
        for (int off = 1; off < 64; off <<= 1) {
            unsigned y = (unsigned)__shfl_up((int)x, off, 64);
            if (lane >= off) x += y;
        }
        if (lane == 63) wt[wv] = x;
        __syncthreads();
        unsigned wadd = 0;
        for (int w = 0; w < wv; ++w) wadd += wt[w];
        unsigned incl = x + wadd;
        unsigned ex0 = incl - v;
        cur[t] = ex0;
        cnt += (float)v;               // count from histogram — no atomic
        __syncthreads();

        // (c) gather + physics + scatter to sorted LDS slot
        #pragma unroll
        for (int k = 0; k < 4; ++k) {
            int i = k * 512 + t;
            if (i >= n) break;
            unsigned pk = vv[k].x;
            int col = (int)(pk & 0x1FFFFu);
            unsigned rl = (pk >> 17) & (NPB - 1);
            float2 dxy = unpackh2(vv[k].y);
            float4 pc = pred[col];
            uint2 pru = ph[rl];
            float2 pxy = unpackh2(pru.x);
            float2 pzw = unpackh2(pru.y);
            float du = pc.x - pxy.x, dv = pc.y - pxy.y;
            float dp = pc.z - pzw.x, dn = pc.w - pzw.y;
            float rx  = 1.0f / (dxy.x + EPS);
            float ry  = 1.0f / (dxy.y + EPS);
            float rx2 = 1.0f / (dxy.x * dxy.x + EPS);
            float ry2 = 1.0f / (dxy.y * dxy.y + EPS);
            float du_dx = du * rx, du_dy = du * ry;
            float dv_dx = dv * rx, dv_dy = dv * ry;
            float nu_eff = NU_MOL + pzw.y;
            float sh = du_dy + dv_dx;
            float div_e = du_dx + dv_dy;
            float mx_e  = dp * rx + nu_eff * du * rx2;
            float my_e  = dp * ry + nu_eff * dv * ry2;
            float str_e = 2.0f * (du_dx * du_dx + dv_dy * dv_dy) + sh * sh;
            unsigned pos = atomicAdd(&cur[rl], 1u);
            pl[pos] = make_uint2(bf16rne(div_e) | (bf16rne(mx_e) << 16),
                                 bf16rne(my_e) | (bf16rne(str_e) << 16));
            smooth += (double)(du * du + dv * dv + dp * dp + dn * dn);
        }
        __syncthreads();

        // (d) register run-sum over contiguous run [ex0, incl) — no atomics
        for (unsigned i = ex0; i < incl; ++i) {
            uint2 pv = pl[i];
            sdiv += bf16dec(pv.x & 0xFFFFu);
            smx  += bf16dec(pv.x >> 16);
            smy  += bf16dec(pv.y & 0xFFFFu);
            sstr += bf16dec(pv.y >> 16);
        }
        __syncthreads();
    }

    // merge partials into global node arrays (coalesced low-contention atomics)
    {
        int n = n0 + t;
        if (n < N) {
            atomicAdd(&g[0 * (size_t)N + n], cnt);
            atomicAdd(&g[1 * (size_t)N + n], sdiv);
            atomicAdd(&g[2 * (size_t)N + n], smx);
            atomicAdd(&g[3 * (size_t)N + n], smy);
            atomicAdd(&g[4 * (size_t)N + n], sstr);
        }
    }

    for (int off = 32; off > 0; off >>= 1)
        smooth += __shfl_down(smooth, off);
    if (lane == 0) sm[wv] = smooth;
    __syncthreads();
    if (t == 0) {
        double tot = 0;
        #pragma unroll
        for (int w = 0; w < 8; ++w) tot += sm[w];
        atomicAdd(&smooth_slots[(b * SPLIT + blockIdx.y) & 63], tot);
    }
}

// Pass 5: node losses from g[5][N]. Separate finalize kernel follows —
// per-block __threadfence fused finalize measured ~+30us (R10-R12).
__global__ __launch_bounds__(256) void node_final_kernel(
    const float* __restrict__ g, const float4* __restrict__ pred,
    const float4* __restrict__ tgt, const unsigned char* __restrict__ wall,
    int N, double* __restrict__ d)
{
    int i = blockIdx.x * 256 + threadIdx.x;
    double v0 = 0, v1 = 0, v2 = 0, v3 = 0, v4 = 0, v5 = 0, v6 = 0, v7 = 0;
    if (i < N) {
        float cnt = g[0 * (size_t)N + i];
        float inv = 1.0f / fmaxf(cnt, 1.0f);
        float div = g[1 * (size_t)N + i] * inv;
        float mx  = g[2 * (size_t)N + i] * inv;
        float my  = g[3 * (size_t)N + i] * inv;
        float sn  = g[4 * (size_t)N + i] * inv;
        float4 p = pred[i];
        float4 tg = tgt[i];
        float prod = p.w * sn;
        float m = wall[i] ? 1.0f : 0.0f;
        float e0 = p.x - tg.x, e1 = p.y - tg.y, e2 = p.z - tg.z, e3 = p.w - tg.w;
        float uv = p.x * p.x + p.y * p.y;
        v0 = (double)(e0 * e0 + e1 * e1 + e2 * e2 + e3 * e3);
        v1 = (double)div * (double)div;
        v2 = (double)mx * (double)mx + (double)my * (double)my;
        v3 = (double)prod * (double)prod;
        v4 = (double)p.w * (double)p.w;
        v5 = (double)m;
        v6 = (double)(m * uv);
        v7 = (double)(m * (uv + p.w * p.w));
    }
    for (int off = 32; off > 0; off >>= 1) {
        v0 += __shfl_down(v0, off); v1 += __shfl_down(v1, off);
        v2 += __shfl_down(v2, off); v3 += __shfl_down(v3, off);
        v4 += __shfl_down(v4, off); v5 += __shfl_down(v5, off);
        v6 += __shfl_down(v6, off); v7 += __shfl_down(v7, off);
    }
    __shared__ double sm[4][8];
    int lane = threadIdx.x & 63, wv = threadIdx.x >> 6;
    if (lane == 0) {
        sm[wv][0] = v0; sm[wv][1] = v1; sm[wv][2] = v2; sm[wv][3] = v3;
        sm[wv][4] = v4; sm[wv][5] = v5; sm[wv][6] = v6; sm[wv][7] = v7;
    }
    __syncthreads();
    if (threadIdx.x < 8) {
        int q = threadIdx.x;
        atomicAdd(&d[q], sm[0][q] + sm[1][q] + sm[2][q] + sm[3][q]);
    }
}

// ===================== fallback path (R1-style, known-correct) =====================

__global__ __launch_bounds__(256) void edge_kernel(
    const void* __restrict__ eidx, const float2* __restrict__ eattr,
    const float4* __restrict__ pred, int E, int N, const int* __restrict__ flag,
    float* __restrict__ a_cnt, float* __restrict__ a_div,
    float* __restrict__ a_mx, float* __restrict__ a_my,
    float* __restrict__ a_str, double* __restrict__ smooth_slots)
{
    const int is64 = *flag;
    const long long* ll = (const long long*)eidx;
    const int* ii = (const int*)eidx;
    double smooth = 0.0;
    const int stride = gridDim.x * blockDim.x;
    for (int e = blockIdx.x * blockDim.x + threadIdx.x; e < E; e += stride) {
        int row, col;
        if (is64) { row = (int)ll[e]; col = (int)ll[(long long)E + e]; }
        else      { row = ii[e];      col = ii[E + e]; }
        row = min(max(row, 0), N - 1);
        col = min(max(col, 0), N - 1);
        float2 dxy = eattr[e];
        float4 pr = pred[row];
        float4 pc = pred[col];
        float du = pc.x - pr.x, dv = pc.y - pr.y;
        float dp = pc.z - pr.z, dn = pc.w - pr.w;
        float rx  = 1.0f / (dxy.x + EPS);
        float ry  = 1.0f / (dxy.y + EPS);
        float rx2 = 1.0f / (dxy.x * dxy.x + EPS);
        float ry2 = 1.0f / (dxy.y * dxy.y + EPS);
        float du_dx = du * rx, du_dy = du * ry;
        float dv_dx = dv * rx, dv_dy = dv * ry;
        float nu_eff = NU_MOL + pr.w;
        atomicAdd(&a_cnt[row], 1.0f);
        atomicAdd(&a_div[row], du_dx + dv_dy);
        atomicAdd(&a_mx[row], dp * rx + nu_eff * du * rx2);
        atomicAdd(&a_my[row], dp * ry + nu_eff * dv * ry2);
        float sh = du_dy + dv_dx;
        atomicAdd(&a_str[row], 2.0f * (du_dx * du_dx + dv_dy * dv_dy) + sh * sh);
        smooth += (double)(du * du + dv * dv + dp * dp + dn * dn);
    }
    for (int off = 32; off > 0; off >>= 1)
        smooth += __shfl_down(smooth, off);
    __shared__ double sm[4];
    int lane = threadIdx.x & 63, wv = threadIdx.x >> 6;
    if (lane == 0) sm[wv] = smooth;
    __syncthreads();
    if (threadIdx.x == 0)
        atomicAdd(&smooth_slots[blockIdx.x & 63], sm[0] + sm[1] + sm[2] + sm[3]);
}

__global__ __launch_bounds__(256) void node_kernel(
    const float4* __restrict__ pred, const float4* __restrict__ tgt,
    const unsigned char* __restrict__ wall, int N,
    const float* __restrict__ a_cnt, const float* __restrict__ a_div,
    const float* __restrict__ a_mx, const float* __restrict__ a_my,
    const float* __restrict__ a_str, double* __restrict__ d)
{
    int i = blockIdx.x * blockDim.x + threadIdx.x;
    double v0 = 0, v1 = 0, v2 = 0, v3 = 0, v4 = 0, v5 = 0, v6 = 0, v7 = 0;
    if (i < N) {
        float4 p = pred[i];
        float4 t = tgt[i];
        float inv = 1.0f / fmaxf(a_cnt[i], 1.0f);
        float div = a_div[i] * inv;
        float mx = a_mx[i] * inv, my = a_my[i] * inv;
        float sn = a_str[i] * inv;
        float prod = p.w * sn;
        float m = wall[i] ? 1.0f : 0.0f;
        float e0 = p.x - t.x, e1 = p.y - t.y, e2 = p.z - t.z, e3 = p.w - t.w;
        float uv = p.x * p.x + p.y * p.y;
        v0 = (double)(e0 * e0 + e1 * e1 + e2 * e2 + e3 * e3);
        v1 = (double)div * (double)div;
        v2 = (double)mx * (double)mx + (double)my * (double)my;
        v3 = (double)prod * (double)prod;
        v4 = (double)p.w * (double)p.w;
        v5 = (double)m;
        v6 = (double)(m * uv);
        v7 = (double)(m * (uv + p.w * p.w));
    }
    for (int off = 32; off > 0; off >>= 1) {
        v0 += __shfl_down(v0, off); v1 += __shfl_down(v1, off);
        v2 += __shfl_down(v2, off); v3 += __shfl_down(v3, off);
        v4 += __shfl_down(v4, off); v5 += __shfl_down(v5, off);
        v6 += __shfl_down(v6, off); v7 += __shfl_down(v7, off);
    }
    __shared__ double sm[4][8];
    int lane = threadIdx.x & 63, wv = threadIdx.x >> 6;
    if (lane == 0) {
        sm[wv][0] = v0; sm[wv][1] = v1; sm[wv][2] = v2; sm[wv][3] = v3;
        sm[wv][4] = v4; sm[wv][5] = v5; sm[wv][6] = v6; sm[wv][7] = v7;
    }
    __syncthreads();
    if (threadIdx.x < 8) {
        int q = threadIdx.x;
        atomicAdd(&d[q], sm[0][q] + sm[1][q] + sm[2][q] + sm[3][q]);
    }
}

// ===================== launch =====================

extern "C" void kernel_launch(void* const* d_in, const int* in_sizes, int n_in,
                              void* d_out, int out_size, void* d_ws, size_t ws_size,
                              hipStream_t stream) {
    const float4* pred = (const float4*)d_in[0];
    const float4* tgt  = (const float4*)d_in[1];
    const float2* eattr = (const float2*)d_in[2];
    const void* eidx = d_in[3];
    const unsigned char* wall = (const unsigned char*)d_in[4];
    int N = in_sizes[0] / 4;
    int E = in_sizes[2] / 2;
    int NB = (N + NPB - 1) / NPB;
    int chunk = (E + NBLK - 1) / NBLK;
    int ntiles = (NB + 63) / 64;

    char* ws = (char*)d_ws;
    double* d = (double*)ws;                 // 8 scalars
    double* smooth_slots = d + 8;            // 64 slots
    int* flag = (int*)(ws + 576);

    size_t off = 1024;
    float* g        = (float*)(ws + off);     off += (size_t)5 * N * 4;  // zeroed
    unsigned* counts = (unsigned*)(ws + off); off += (size_t)NBLK * NBP * 4;
    unsigned* gsum   = (unsigned*)(ws + off); off += (size_t)NGRP * NBP * 4;
    unsigned* base   = (unsigned*)(ws + off); off += (size_t)(NB + 1) * 4;
    off = (off + 15) & ~(size_t)15;
    uint2* vals      = (uint2*)(ws + off);    off += (size_t)E * 8;
    size_t need_fast = off;

    bool fast = (NB <= MAXNB) && (N <= 131072) && (chunk <= CMAX) &&
                (ws_size >= need_fast);

    if (fast) {
        hipMemsetAsync(d_ws, 0, 1024 + (size_t)5 * N * 4, stream);
        detect_idx_dtype<<<1, 1, 0, stream>>>(eidx, N, flag);
        count_kernel<<<NBLK, 256, 0, stream>>>(eidx, E, N, NB, flag, counts);
        group_sums_kernel<<<dim3(NGRP, ntiles), 256, 0, stream>>>(counts, gsum, NB);
        scan_base_kernel<<<1, 512, 0, stream>>>(gsum, base, NB);
        local_scan_kernel<<<dim3(NGRP, ntiles), 256, 0, stream>>>(counts, gsum, NB);
        scatter_kernel<<<NBLK, 256, 0, stream>>>(eidx, eattr, E, N, NB, flag,
                                                 counts, vals);
        accum_kernel<<<dim3(NB, SPLIT), 512, 0, stream>>>(vals, base, pred, N,
                                                          g, smooth_slots);
        node_final_kernel<<<(N + 255) / 256, 256, 0, stream>>>(g, pred, tgt, wall,
                                                               N, d);
        finalize_kernel<<<1, 1, 0, stream>>>(d, smooth_slots, N, E, (float*)d_out);
    } else {
        float* arrays = (float*)(ws + 1024);
        float* a_cnt = arrays + (size_t)0 * N;
        float* a_div = arrays + (size_t)1 * N;
        float* a_mx  = arrays + (size_t)2 * N;
        float* a_my  = arrays + (size_t)3 * N;
        float* a_str = arrays + (size_t)4 * N;
        size_t zbytes = 1024 + (size_t)5 * N * sizeof(float);
        hipMemsetAsync(d_ws, 0, zbytes, stream);
        detect_idx_dtype<<<1, 1, 0, stream>>>(eidx, N, flag);
        edge_kernel<<<4096, 256, 0, stream>>>(eidx, eattr, pred, E, N, flag,
                                              a_cnt, a_div, a_mx, a_my, a_str,
                                              smooth_slots);
        node_kernel<<<(N + 255) / 256, 256, 0, stream>>>(pred, tgt, wall, N,
                                                         a_cnt, a_div, a_mx, a_my,
                                                         a_str, d);
        finalize_kernel<<<1, 1, 0, stream>>>(d, smooth_slots, N, E, (float*)d_out);
    }
}